// Round 1
// baseline (8489.522 us; speedup 1.0000x reference)
//
#include <hip/hip_runtime.h>
#include <cstdint>
#include <cstddef>

#define NEG_INF (-3.0e38f)

// ---------------- prep: normalize keys (transposed) + hard (row-major), c0 ----------------
__global__ void prep_norm_k(const float* __restrict__ keys,
                            const float* __restrict__ hard,
                            float* __restrict__ knT,   // [128][800]
                            float* __restrict__ hn) {  // [800][128]
    int m = blockIdx.x;      // 0..799
    int c = threadIdx.x;     // 0..127
    float kv = keys[m * 128 + c];
    float hv = hard[m * 128 + c];
    __shared__ float s1[128];
    __shared__ float s2[128];
    s1[c] = kv * kv;
    s2[c] = hv * hv;
    __syncthreads();
    for (int off = 64; off > 0; off >>= 1) {
        if (c < off) { s1[c] += s1[c + off]; s2[c] += s2[c + off]; }
        __syncthreads();
    }
    float ks = 1.0f / fmaxf(sqrtf(s1[0]), 1e-12f);
    float hs = 1.0f / fmaxf(sqrtf(s2[0]), 1e-12f);
    knT[c * 800 + m] = kv * ks;
    hn[m * 128 + c]  = hv * hs;
}

__global__ void prep_c0_k(const float* __restrict__ values, float* __restrict__ c0) {
    int c = threadIdx.x;  // 128 threads
    float s = 0.f;
    for (int m = 0; m < 10; ++m) s += values[m * 128 + c];
    c0[c] = s * 0.1f;
}

// ---------------- conv3x3(1->Cout) + relu + pool2x2, input masked to [lo,hi) ----------------
__global__ void conv1pool_k(const float* __restrict__ x,   // (16,1,256,256)
                            const float* __restrict__ w,   // (Cout,1,3,3)
                            const float* __restrict__ bias,
                            float* __restrict__ out,       // (16,Cout,128,128)
                            int Cout, int lo, int hi) {
    int bx = blockIdx.x;
    int b = bx / Cout, co = bx % Cout;
    float wr[9];
#pragma unroll
    for (int t = 0; t < 9; ++t) wr[t] = w[co * 9 + t];
    float bv = bias[co];
    const float* xb = x + (size_t)b * 65536;
    float* ob = out + ((size_t)b * Cout + co) * 16384;
    for (int idx = threadIdx.x; idx < 16384; idx += 256) {
        int ph = idx >> 7, pw = idx & 127;
        float best = NEG_INF;
#pragma unroll
        for (int r = 0; r < 2; ++r) {
#pragma unroll
            for (int s = 0; s < 2; ++s) {
                int oh = 2 * ph + r, ow = 2 * pw + s;
                float acc = bv;
#pragma unroll
                for (int kh = 0; kh < 3; ++kh) {
#pragma unroll
                    for (int kw = 0; kw < 3; ++kw) {
                        int ih = oh + kh - 1, iw = ow + kw - 1;
                        float v = (ih >= lo && ih < hi && iw >= lo && iw < hi)
                                      ? xb[ih * 256 + iw] : 0.f;
                        acc += v * wr[kh * 3 + kw];
                    }
                }
                best = fmaxf(best, acc);
            }
        }
        ob[idx] = fmaxf(best, 0.f);
    }
}

// ---------------- center conv2 (32->128) + relu + pool, region [23,40]^2 only ----------------
__global__ void ce2_k(const float* __restrict__ zc1,  // (16,32,128,128)
                      const float* __restrict__ w,    // (128,32,3,3)
                      const float* __restrict__ bias,
                      float* __restrict__ zc) {       // (16,128,64,64) region only
    int bx = blockIdx.x;
    int b = bx >> 7, co = bx & 127;
    float bv = bias[co];
    const float* ib = zc1 + (size_t)b * 32 * 16384;
    for (int idx = threadIdx.x; idx < 324; idx += 256) {
        int h = 23 + idx / 18, ww = 23 + idx % 18;
        float a00 = bv, a01 = bv, a10 = bv, a11 = bv;
        for (int ci = 0; ci < 32; ++ci) {
            const float* p = ib + ci * 16384 + (2 * h - 1) * 128 + (2 * ww - 1);
            const float* wp = w + ((size_t)co * 32 + ci) * 9;
            float win[4][4];
#pragma unroll
            for (int r = 0; r < 4; ++r)
#pragma unroll
                for (int s = 0; s < 4; ++s) win[r][s] = p[r * 128 + s];
#pragma unroll
            for (int kh = 0; kh < 3; ++kh) {
#pragma unroll
                for (int kw = 0; kw < 3; ++kw) {
                    float wv = wp[kh * 3 + kw];
                    a00 += win[kh][kw] * wv;
                    a01 += win[kh][kw + 1] * wv;
                    a10 += win[kh + 1][kw] * wv;
                    a11 += win[kh + 1][kw + 1] * wv;
                }
            }
        }
        float mx = fmaxf(fmaxf(a00, a01), fmaxf(a10, a11));
        zc[((size_t)b * 128 + co) * 4096 + h * 64 + ww] = fmaxf(mx, 0.f);
    }
}

// ---------------- skip conv2 (16->128) + relu + pool, full ----------------
__global__ void se2_k(const float* __restrict__ zs1,  // (16,16,128,128)
                      const float* __restrict__ w,    // (128,16,3,3)
                      const float* __restrict__ bias,
                      float* __restrict__ zs) {       // (16,128,64,64)
    int bx = blockIdx.x;
    int b = bx >> 7, co = bx & 127;
    float bv = bias[co];
    const float* ib = zs1 + (size_t)b * 16 * 16384;
    for (int idx = threadIdx.x; idx < 4096; idx += 256) {
        int h = idx >> 6, ww = idx & 63;
        int r0 = 2 * h - 1, c0_ = 2 * ww - 1;
        float a00 = bv, a01 = bv, a10 = bv, a11 = bv;
        for (int ci = 0; ci < 16; ++ci) {
            const float* p = ib + ci * 16384;
            const float* wp = w + ((size_t)co * 16 + ci) * 9;
            float win[4][4];
#pragma unroll
            for (int r = 0; r < 4; ++r) {
                int rr = r0 + r;
                bool vr = (rr >= 0 && rr < 128);
#pragma unroll
                for (int s = 0; s < 4; ++s) {
                    int cc = c0_ + s;
                    win[r][s] = (vr && cc >= 0 && cc < 128) ? p[rr * 128 + cc] : 0.f;
                }
            }
#pragma unroll
            for (int kh = 0; kh < 3; ++kh) {
#pragma unroll
                for (int kw = 0; kw < 3; ++kw) {
                    float wv = wp[kh * 3 + kw];
                    a00 += win[kh][kw] * wv;
                    a01 += win[kh][kw + 1] * wv;
                    a10 += win[kh + 1][kw] * wv;
                    a11 += win[kh + 1][kw + 1] * wv;
                }
            }
        }
        float mx = fmaxf(fmaxf(a00, a01), fmaxf(a10, a11));
        zs[((size_t)b * 128 + co) * 4096 + idx] = fmaxf(mx, 0.f);
    }
}

// ---------------- center matching: one wave per in-region query ----------------
__global__ void __launch_bounds__(64) match_center_k(
        const float* __restrict__ zc,     // (16,128,64,64)
        const float* __restrict__ knT,    // [128][800] normalized
        const float* __restrict__ values, // (800,128)
        float* __restrict__ dcat) {       // (16,256,64,64), ch 0..127
    int bq = blockIdx.x;
    int b = bq / 324, q = bq % 324;
    int h = 23 + q / 18, ww = 23 + q % 18;
    int p = h * 64 + ww;
    int lane = threadIdx.x;
    __shared__ float qs[128];
    const float* zb = zc + ((size_t)b * 128) * 4096 + p;
    float v0 = zb[(size_t)lane * 4096];
    float v1 = zb[(size_t)(lane + 64) * 4096];
    float ss = v0 * v0 + v1 * v1;
#pragma unroll
    for (int off = 32; off > 0; off >>= 1) ss += __shfl_xor(ss, off);
    float sc = 1.0f / fmaxf(sqrtf(ss), 1e-12f);
    qs[lane] = v0 * sc;
    qs[lane + 64] = v1 * sc;
    __syncthreads();

    float sim[13];
#pragma unroll
    for (int k = 0; k < 13; ++k) sim[k] = 0.f;
    for (int c = 0; c < 128; ++c) {
        float qc = qs[c];
        const float* kr = knT + c * 800 + lane;
#pragma unroll
        for (int k = 0; k < 13; ++k) {
            int m = lane + (k << 6);
            if (m < 800) sim[k] += qc * kr[k << 6];
        }
    }
#pragma unroll
    for (int k = 0; k < 13; ++k)
        if (lane + (k << 6) >= 800) sim[k] = NEG_INF;

    // extract top-11 (values desc, ties -> lower index) like lax.top_k
    float topv[11]; int topm[11];
#pragma unroll
    for (int t = 0; t < 11; ++t) {
        float bvv = NEG_INF; int bm = 0x7fffffff;
#pragma unroll
        for (int k = 0; k < 13; ++k) {
            if (sim[k] > bvv) { bvv = sim[k]; bm = lane + (k << 6); }
        }
#pragma unroll
        for (int off = 32; off > 0; off >>= 1) {
            float ov = __shfl_xor(bvv, off);
            int om = __shfl_xor(bm, off);
            if (ov > bvv || (ov == bvv && om < bm)) { bvv = ov; bm = om; }
        }
        topv[t] = bvv; topm[t] = bm;
        if ((bm & 63) == lane) {
            int kk = bm >> 6;
#pragma unroll
            for (int k = 0; k < 13; ++k)
                if (k == kk) sim[k] = NEG_INF;
        }
    }
    // fp64 refinement of the 10/11 boundary (selection robustness vs fp64 ref)
    if (topv[9] - topv[10] < 1e-4f) {
        double s9 = 0.0, s10 = 0.0;
        for (int c = 0; c < 128; ++c) {
            double qc = (double)qs[c];
            s9  += qc * (double)knT[c * 800 + topm[9]];
            s10 += qc * (double)knT[c * 800 + topm[10]];
        }
        if ((s10 > s9) || (s10 == s9 && topm[10] < topm[9])) {
            topv[9] = topv[10]; topm[9] = topm[10];
        }
    }
    // softmax over top-10 + weighted gather
    float mx = topv[0];
    float e[10], ssum = 0.f;
#pragma unroll
    for (int t = 0; t < 10; ++t) { e[t] = expf(topv[t] - mx); ssum += e[t]; }
    float inv = 1.0f / ssum;
    float o0 = 0.f, o1 = 0.f;
#pragma unroll
    for (int t = 0; t < 10; ++t) {
        float wt = e[t] * inv;
        const float* vr = values + (size_t)topm[t] * 128;
        o0 += wt * vr[lane];
        o1 += wt * vr[lane + 64];
    }
    float* ob = dcat + ((size_t)b * 256) * 4096 + p;
    ob[(size_t)lane * 4096] = o0;
    ob[(size_t)(lane + 64) * 4096] = o1;
}

// ---------------- constant fill for out-of-region center matches ----------------
__global__ void fill_c0_k(const float* __restrict__ c0, float* __restrict__ dcat) {
    int idx = blockIdx.x * 256 + threadIdx.x;  // 16*128*4096
    int p = idx & 4095;
    int c = (idx >> 12) & 127;
    int b = idx >> 19;
    int h = p >> 6, ww = p & 63;
    if (h >= 23 && h <= 40 && ww >= 23 && ww <= 40) return;
    dcat[((size_t)b * 256 + c) * 4096 + p] = c0[c];
}

// ---------------- skip matching: argmax over 800 normalized hard keys ----------------
__global__ void __launch_bounds__(256, 1) match_skip_k(
        const float* __restrict__ zs,    // (16,128,64,64)
        const float* __restrict__ hn,    // (800,128) normalized
        const float* __restrict__ hard,  // (800,128) raw
        float* __restrict__ dcat) {      // ch 128..255
    int qid = blockIdx.x * 256 + threadIdx.x;  // 0..65535
    int b = qid >> 12, p = qid & 4095;
    const float* zb = zs + ((size_t)b * 128) * 4096 + p;
    float q[128];
    float qn2 = 0.f;
#pragma unroll
    for (int c = 0; c < 128; ++c) { q[c] = zb[(size_t)c * 4096]; qn2 += q[c] * q[c]; }
    float v1 = NEG_INF, v2 = NEG_INF; int i1 = 0, i2 = 0;
    for (int m = 0; m < 800; ++m) {
        const float4* hm = (const float4*)(hn + (size_t)m * 128);
        float s = 0.f;
#pragma unroll
        for (int c4 = 0; c4 < 32; ++c4) {
            float4 kv = hm[c4];
            s += q[c4 * 4 + 0] * kv.x + q[c4 * 4 + 1] * kv.y +
                 q[c4 * 4 + 2] * kv.z + q[c4 * 4 + 3] * kv.w;
        }
        if (s > v1) { v2 = v1; i2 = i1; v1 = s; i1 = m; }
        else if (s > v2) { v2 = s; i2 = m; }
    }
    int bi = i1;
    float tau = 1e-4f * sqrtf(qn2) + 1e-12f;
    if (v1 - v2 < tau) {  // fp64 tie-break (matches fp64 ref argmax)
        double s1 = 0.0, s2 = 0.0;
        const float* h1 = hn + (size_t)i1 * 128;
        const float* h2 = hn + (size_t)i2 * 128;
        for (int c = 0; c < 128; ++c) {
            double qc = (double)q[c];
            s1 += qc * (double)h1[c];
            s2 += qc * (double)h2[c];
        }
        bi = ((s2 > s1) || (s2 == s1 && i2 < i1)) ? i2 : i1;
    }
    float* ob = dcat + ((size_t)b * 256 + 128) * 4096 + p;
    const float* hr = hard + (size_t)bi * 128;
#pragma unroll
    for (int c = 0; c < 128; ++c) ob[(size_t)c * 4096] = hr[c];
}

// ---------------- decoder conv1: (256->64) 3x3 + relu ----------------
__global__ void dec1_k(const float* __restrict__ dcat, // (16,256,64,64)
                       const float* __restrict__ w,    // (64,256,3,3)
                       const float* __restrict__ bias,
                       float* __restrict__ d1) {       // (16,64,64,64)
    int bx = blockIdx.x;
    int b = bx >> 6, co = bx & 63;
    float bv = bias[co];
    const float* ib = dcat + (size_t)b * 256 * 4096;
    const float* wb = w + (size_t)co * 256 * 9;
    float* ob = d1 + ((size_t)b * 64 + co) * 4096;
    for (int idx = threadIdx.x; idx < 4096; idx += 256) {
        int h = idx >> 6, ww = idx & 63;
        bool hm = h > 0, hp = h < 63, wm = ww > 0, wp = ww < 63;
        float acc = bv;
        for (int ci = 0; ci < 256; ++ci) {
            const float* p = ib + (size_t)ci * 4096 + idx;
            const float* wp9 = wb + ci * 9;
            float x00 = (hm && wm) ? p[-65] : 0.f;
            float x01 = hm ? p[-64] : 0.f;
            float x02 = (hm && wp) ? p[-63] : 0.f;
            float x10 = wm ? p[-1] : 0.f;
            float x11 = p[0];
            float x12 = wp ? p[1] : 0.f;
            float x20 = (hp && wm) ? p[63] : 0.f;
            float x21 = hp ? p[64] : 0.f;
            float x22 = (hp && wp) ? p[65] : 0.f;
            acc += x00 * wp9[0] + x01 * wp9[1] + x02 * wp9[2] +
                   x10 * wp9[3] + x11 * wp9[4] + x12 * wp9[5] +
                   x20 * wp9[6] + x21 * wp9[7] + x22 * wp9[8];
        }
        ob[idx] = fmaxf(acc, 0.f);
    }
}

// ---------------- transposed conv stride2 k4 pad-equiv + relu ----------------
__global__ void tconv_k(const float* __restrict__ x,  // (16,Cin,H,H)
                        const float* __restrict__ w,  // (Cin,Cout,4,4)
                        const float* __restrict__ bias,
                        float* __restrict__ out,      // (16,Cout,2H,2H)
                        int Cin, int Cout, int H) {
    int bx = blockIdx.x;
    int b = bx / Cout, o = bx % Cout;
    int HO = 2 * H;
    float bv = bias[o];
    const float* xb = x + (size_t)b * Cin * H * H;
    float* ob = out + ((size_t)b * Cout + o) * HO * HO;
    int total = HO * HO;
    for (int idx = threadIdx.x; idx < total; idx += 256) {
        int r = idx / HO, c = idx % HO;
        int kh_a = r & 1, kh_b = kh_a + 2;
        int ih_a = (r + kh_a - 2) >> 1;
        int ih_b = (r + kh_b - 2) >> 1;
        bool va = (ih_a >= 0 && ih_a < H);
        bool vb = (ih_b >= 0 && ih_b < H);
        int kw_a = c & 1, kw_b = kw_a + 2;
        int iw_a = (c + kw_a - 2) >> 1;
        int iw_b = (c + kw_b - 2) >> 1;
        bool ua = (iw_a >= 0 && iw_a < H);
        bool ub = (iw_b >= 0 && iw_b < H);
        int wo_aa = (3 - kh_a) * 4 + (3 - kw_a);
        int wo_ab = (3 - kh_a) * 4 + (3 - kw_b);
        int wo_ba = (3 - kh_b) * 4 + (3 - kw_a);
        int wo_bb = (3 - kh_b) * 4 + (3 - kw_b);
        float acc = bv;
        for (int ci = 0; ci < Cin; ++ci) {
            const float* xp = xb + (size_t)ci * H * H;
            const float* wp = w + ((size_t)ci * Cout + o) * 16;
            float xaa = (va && ua) ? xp[ih_a * H + iw_a] : 0.f;
            float xab = (va && ub) ? xp[ih_a * H + iw_b] : 0.f;
            float xba = (vb && ua) ? xp[ih_b * H + iw_a] : 0.f;
            float xbb = (vb && ub) ? xp[ih_b * H + iw_b] : 0.f;
            acc += xaa * wp[wo_aa] + xab * wp[wo_ab] + xba * wp[wo_ba] + xbb * wp[wo_bb];
        }
        ob[idx] = fmaxf(acc, 0.f);
    }
}

// ---------------- final conv (16->1) 3x3, no relu ----------------
__global__ void final_k(const float* __restrict__ t2,  // (16,16,256,256)
                        const float* __restrict__ w,   // (1,16,3,3)
                        const float* __restrict__ bias,
                        float* __restrict__ out) {     // (16,1,256,256)
    int idx = blockIdx.x * 256 + threadIdx.x;  // 16*65536
    int b = idx >> 16, p = idx & 65535;
    int h = p >> 8, c = p & 255;
    const float* tb = t2 + (size_t)b * 16 * 65536;
    bool hm = h > 0, hp = h < 255, wm = c > 0, wp = c < 255;
    float acc = bias[0];
    for (int ci = 0; ci < 16; ++ci) {
        const float* pp = tb + (size_t)ci * 65536 + p;
        const float* w9 = w + ci * 9;
        float x00 = (hm && wm) ? pp[-257] : 0.f;
        float x01 = hm ? pp[-256] : 0.f;
        float x02 = (hm && wp) ? pp[-255] : 0.f;
        float x10 = wm ? pp[-1] : 0.f;
        float x11 = pp[0];
        float x12 = wp ? pp[1] : 0.f;
        float x20 = (hp && wm) ? pp[255] : 0.f;
        float x21 = hp ? pp[256] : 0.f;
        float x22 = (hp && wp) ? pp[257] : 0.f;
        acc += x00 * w9[0] + x01 * w9[1] + x02 * w9[2] +
               x10 * w9[3] + x11 * w9[4] + x12 * w9[5] +
               x20 * w9[6] + x21 * w9[7] + x22 * w9[8];
    }
    out[idx] = acc;
}

// ---------------- launch ----------------
extern "C" void kernel_launch(void* const* d_in, const int* in_sizes, int n_in,
                              void* d_out, int out_size, void* d_ws, size_t ws_size,
                              hipStream_t stream) {
    (void)in_sizes; (void)n_in; (void)out_size; (void)ws_size;
    const float* x     = (const float*)d_in[0];
    const float* cw1   = (const float*)d_in[1];
    const float* cb1   = (const float*)d_in[2];
    const float* cw2   = (const float*)d_in[3];
    const float* cb2   = (const float*)d_in[4];
    const float* sw1   = (const float*)d_in[5];
    const float* sb1   = (const float*)d_in[6];
    const float* sw2   = (const float*)d_in[7];
    const float* sb2   = (const float*)d_in[8];
    const float* mkeys = (const float*)d_in[9];
    const float* mvals = (const float*)d_in[10];
    const float* mhard = (const float*)d_in[11];
    const float* dw1   = (const float*)d_in[12];
    const float* db1   = (const float*)d_in[13];
    const float* tw1   = (const float*)d_in[14];
    const float* tb1   = (const float*)d_in[15];
    const float* tw2   = (const float*)d_in[16];
    const float* tb2   = (const float*)d_in[17];
    const float* dw2   = (const float*)d_in[18];
    const float* db2   = (const float*)d_in[19];
    float* out = (float*)d_out;
    float* ws  = (float*)d_ws;

    // workspace layout (floats)
    const size_t OFF_KN  = 0;          // knT: 128*800
    const size_t OFF_HN  = 102400;     // hn:  800*128
    const size_t OFF_C0  = 204800;     // c0:  128
    const size_t OFF_R14 = 204928;     // 8388608: zc1 -> zs -> t1
    const size_t OFF_R2  = OFF_R14 + 8388608;  // 8388608: zc
    const size_t OFF_R3  = OFF_R2 + 8388608;   // 4194304: zs1 -> d1
    const size_t OFF_R5  = OFF_R3 + 4194304;   // 16777216: dcat -> t2

    float* knT  = ws + OFF_KN;
    float* hn   = ws + OFF_HN;
    float* c0   = ws + OFF_C0;
    float* zc1  = ws + OFF_R14;
    float* zs   = ws + OFF_R14;
    float* t1   = ws + OFF_R14;
    float* zc   = ws + OFF_R2;
    float* zs1  = ws + OFF_R3;
    float* d1b  = ws + OFF_R3;
    float* dcat = ws + OFF_R5;
    float* t2   = ws + OFF_R5;

    prep_norm_k<<<800, 128, 0, stream>>>(mkeys, mhard, knT, hn);
    prep_c0_k<<<1, 128, 0, stream>>>(mvals, c0);

    conv1pool_k<<<16 * 32, 256, 0, stream>>>(x, cw1, cb1, zc1, 32, 96, 160);
    conv1pool_k<<<16 * 16, 256, 0, stream>>>(x, sw1, sb1, zs1, 16, 0, 256);
    ce2_k<<<16 * 128, 256, 0, stream>>>(zc1, cw2, cb2, zc);
    se2_k<<<16 * 128, 256, 0, stream>>>(zs1, sw2, sb2, zs);  // overwrites zc1 (dead)

    match_center_k<<<16 * 324, 64, 0, stream>>>(zc, knT, mvals, dcat);
    fill_c0_k<<<32768, 256, 0, stream>>>(c0, dcat);
    match_skip_k<<<256, 256, 0, stream>>>(zs, hn, mhard, dcat);

    dec1_k<<<16 * 64, 256, 0, stream>>>(dcat, dw1, db1, d1b);            // overwrites zs1 (dead)
    tconv_k<<<16 * 32, 256, 0, stream>>>(d1b, tw1, tb1, t1, 64, 32, 64); // overwrites zs (dead)
    tconv_k<<<16 * 16, 256, 0, stream>>>(t1, tw2, tb2, t2, 32, 16, 128); // overwrites dcat (dead)
    final_k<<<4096, 256, 0, stream>>>(t2, dw2, db2, out);
}

// Round 3
// 2997.321 us; speedup vs baseline: 2.8324x; 2.8324x over previous
//
#include <hip/hip_runtime.h>
#include <cstdint>
#include <cstddef>

#define NEG_INF (-3.0e38f)

// ---------------- prep: normalize keys (transposed) + hard (row-major) ----------------
__global__ void prep_norm_k(const float* __restrict__ keys,
                            const float* __restrict__ hard,
                            float* __restrict__ knT,   // [128][800]
                            float* __restrict__ hn) {  // [800][128]
    int m = blockIdx.x;      // 0..799
    int c = threadIdx.x;     // 0..127
    float kv = keys[m * 128 + c];
    float hv = hard[m * 128 + c];
    __shared__ float s1[128];
    __shared__ float s2[128];
    s1[c] = kv * kv;
    s2[c] = hv * hv;
    __syncthreads();
    for (int off = 64; off > 0; off >>= 1) {
        if (c < off) { s1[c] += s1[c + off]; s2[c] += s2[c + off]; }
        __syncthreads();
    }
    float ks = 1.0f / fmaxf(sqrtf(s1[0]), 1e-12f);
    float hs = 1.0f / fmaxf(sqrtf(s2[0]), 1e-12f);
    knT[c * 800 + m] = kv * ks;
    hn[m * 128 + c]  = hv * hs;
}

__global__ void prep_c0_k(const float* __restrict__ values, float* __restrict__ c0) {
    int c = threadIdx.x;  // 128 threads
    float s = 0.f;
    for (int m = 0; m < 10; ++m) s += values[m * 128 + c];
    c0[c] = s * 0.1f;
}

// ---------------- center conv1+pool: only pooled rect [45,83)^2, 16 co per block ----------------
__global__ void ce1_k(const float* __restrict__ x,   // (16,1,256,256)
                      const float* __restrict__ w,   // (32,1,3,3)
                      const float* __restrict__ bias,
                      float* __restrict__ out) {     // (16,32,128,128) rect only
    int bx = blockIdx.x;            // 16 b * 2 cog * 6 tiles
    int b = bx / 12, rem = bx % 12;
    int cog = rem / 6, tile = rem % 6;
    int idx = tile * 256 + threadIdx.x;
    if (idx >= 1444) return;
    int ph = 45 + idx / 38, pw = 45 + idx % 38;
    const float* xb = x + (size_t)b * 65536;
    float win[4][4];
#pragma unroll
    for (int r = 0; r < 4; ++r) {
        int ih = 2 * ph - 1 + r;
        bool vr = (ih >= 96 && ih < 160);
#pragma unroll
        for (int c = 0; c < 4; ++c) {
            int iw = 2 * pw - 1 + c;
            win[r][c] = (vr && iw >= 96 && iw < 160) ? xb[ih * 256 + iw] : 0.f;
        }
    }
#pragma unroll
    for (int co8 = 0; co8 < 16; ++co8) {
        int co = cog * 16 + co8;
        const float* w9 = w + co * 9;
        float bv = bias[co];
        float a00 = bv, a01 = bv, a10 = bv, a11 = bv;
#pragma unroll
        for (int kh = 0; kh < 3; ++kh)
#pragma unroll
            for (int kw = 0; kw < 3; ++kw) {
                float wv = w9[kh * 3 + kw];
                a00 += win[kh][kw] * wv;
                a01 += win[kh][kw + 1] * wv;
                a10 += win[kh + 1][kw] * wv;
                a11 += win[kh + 1][kw + 1] * wv;
            }
        float mx = fmaxf(fmaxf(a00, a01), fmaxf(a10, a11));
        out[((size_t)b * 32 + co) * 16384 + ph * 128 + pw] = fmaxf(mx, 0.f);
    }
}

// ---------------- skip conv1+pool: full, 16 co per thread ----------------
__global__ void se1_k(const float* __restrict__ x,   // (16,1,256,256)
                      const float* __restrict__ w,   // (16,1,3,3)
                      const float* __restrict__ bias,
                      float* __restrict__ out) {     // (16,16,128,128)
    int bx = blockIdx.x;            // 16 b * 64 tiles
    int b = bx >> 6, tile = bx & 63;
    int idx = tile * 256 + threadIdx.x;   // 0..16383
    int ph = idx >> 7, pw = idx & 127;
    const float* xb = x + (size_t)b * 65536;
    float win[4][4];
#pragma unroll
    for (int r = 0; r < 4; ++r) {
        int ih = 2 * ph - 1 + r;
        bool vr = (ih >= 0 && ih < 256);
#pragma unroll
        for (int c = 0; c < 4; ++c) {
            int iw = 2 * pw - 1 + c;
            win[r][c] = (vr && iw >= 0 && iw < 256) ? xb[ih * 256 + iw] : 0.f;
        }
    }
#pragma unroll
    for (int co = 0; co < 16; ++co) {
        const float* w9 = w + co * 9;
        float bv = bias[co];
        float a00 = bv, a01 = bv, a10 = bv, a11 = bv;
#pragma unroll
        for (int kh = 0; kh < 3; ++kh)
#pragma unroll
            for (int kw = 0; kw < 3; ++kw) {
                float wv = w9[kh * 3 + kw];
                a00 += win[kh][kw] * wv;
                a01 += win[kh][kw + 1] * wv;
                a10 += win[kh + 1][kw] * wv;
                a11 += win[kh + 1][kw + 1] * wv;
            }
        float mx = fmaxf(fmaxf(a00, a01), fmaxf(a10, a11));
        out[((size_t)b * 16 + co) * 16384 + idx] = fmaxf(mx, 0.f);
    }
}

// ---------------- center conv2 (32->128) + relu + pool, region [23,40]^2 only ----------------
__global__ void ce2_k(const float* __restrict__ zc1,  // (16,32,128,128)
                      const float* __restrict__ w,    // (128,32,3,3)
                      const float* __restrict__ bias,
                      float* __restrict__ zc) {       // (16,128,64,64) region only
    int bx = blockIdx.x;
    int b = bx >> 7, co = bx & 127;
    float bv = bias[co];
    const float* ib = zc1 + (size_t)b * 32 * 16384;
    for (int idx = threadIdx.x; idx < 324; idx += 256) {
        int h = 23 + idx / 18, ww = 23 + idx % 18;
        float a00 = bv, a01 = bv, a10 = bv, a11 = bv;
        for (int ci = 0; ci < 32; ++ci) {
            const float* p = ib + ci * 16384 + (2 * h - 1) * 128 + (2 * ww - 1);
            const float* wp = w + ((size_t)co * 32 + ci) * 9;
            float win[4][4];
#pragma unroll
            for (int r = 0; r < 4; ++r)
#pragma unroll
                for (int s = 0; s < 4; ++s) win[r][s] = p[r * 128 + s];
#pragma unroll
            for (int kh = 0; kh < 3; ++kh) {
#pragma unroll
                for (int kw = 0; kw < 3; ++kw) {
                    float wv = wp[kh * 3 + kw];
                    a00 += win[kh][kw] * wv;
                    a01 += win[kh][kw + 1] * wv;
                    a10 += win[kh + 1][kw] * wv;
                    a11 += win[kh + 1][kw + 1] * wv;
                }
            }
        }
        float mx = fmaxf(fmaxf(a00, a01), fmaxf(a10, a11));
        zc[((size_t)b * 128 + co) * 4096 + h * 64 + ww] = fmaxf(mx, 0.f);
    }
}

// ---------------- skip conv2 (16->128) + relu + pool, 8 co per thread ----------------
__global__ void se2_v2(const float* __restrict__ zs1,  // (16,16,128,128)
                       const float* __restrict__ w,    // (128,16,3,3)
                       const float* __restrict__ bias,
                       float* __restrict__ zs) {       // (16,128,64,64)
    int bx = blockIdx.x;            // 16 b * 16 cog * 16 tiles = 4096
    int b = bx >> 8, rem = bx & 255;
    int cog = rem >> 4, tile = rem & 15;
    int px = tile * 256 + threadIdx.x;  // 0..4095
    int ph = px >> 6, pw = px & 63;
    const float* ib = zs1 + (size_t)b * 16 * 16384;
    float acc[8][4];
#pragma unroll
    for (int c8 = 0; c8 < 8; ++c8)
#pragma unroll
        for (int t = 0; t < 4; ++t) acc[c8][t] = 0.f;
    for (int ci = 0; ci < 16; ++ci) {
        const float* p = ib + ci * 16384;
        float win[4][4];
#pragma unroll
        for (int r = 0; r < 4; ++r) {
            int rr = 2 * ph - 1 + r;
            bool vr = (rr >= 0 && rr < 128);
#pragma unroll
            for (int s = 0; s < 4; ++s) {
                int cc = 2 * pw - 1 + s;
                win[r][s] = (vr && cc >= 0 && cc < 128) ? p[rr * 128 + cc] : 0.f;
            }
        }
#pragma unroll
        for (int c8 = 0; c8 < 8; ++c8) {
            const float* w9 = w + ((size_t)(cog * 8 + c8) * 16 + ci) * 9;
#pragma unroll
            for (int kh = 0; kh < 3; ++kh)
#pragma unroll
                for (int kw = 0; kw < 3; ++kw) {
                    float wv = w9[kh * 3 + kw];
                    acc[c8][0] += win[kh][kw] * wv;
                    acc[c8][1] += win[kh][kw + 1] * wv;
                    acc[c8][2] += win[kh + 1][kw] * wv;
                    acc[c8][3] += win[kh + 1][kw + 1] * wv;
                }
        }
    }
#pragma unroll
    for (int c8 = 0; c8 < 8; ++c8) {
        int co = cog * 8 + c8;
        float bv = bias[co];
        float mx = fmaxf(fmaxf(acc[c8][0], acc[c8][1]), fmaxf(acc[c8][2], acc[c8][3])) + bv;
        zs[((size_t)b * 128 + co) * 4096 + px] = fmaxf(mx, 0.f);
    }
}

// ---------------- center matching: one wave per in-region query ----------------
__global__ void __launch_bounds__(64) match_center_k(
        const float* __restrict__ zc,     // (16,128,64,64)
        const float* __restrict__ knT,    // [128][800] normalized
        const float* __restrict__ values, // (800,128)
        float* __restrict__ dcat) {       // (16,256,64,64), ch 0..127
    int bq = blockIdx.x;
    int b = bq / 324, q = bq % 324;
    int h = 23 + q / 18, ww = 23 + q % 18;
    int p = h * 64 + ww;
    int lane = threadIdx.x;
    __shared__ float qs[128];
    const float* zb = zc + ((size_t)b * 128) * 4096 + p;
    float v0 = zb[(size_t)lane * 4096];
    float v1 = zb[(size_t)(lane + 64) * 4096];
    float ss = v0 * v0 + v1 * v1;
#pragma unroll
    for (int off = 32; off > 0; off >>= 1) ss += __shfl_xor(ss, off);
    float sc = 1.0f / fmaxf(sqrtf(ss), 1e-12f);
    qs[lane] = v0 * sc;
    qs[lane + 64] = v1 * sc;
    __syncthreads();

    float sim[13];
#pragma unroll
    for (int k = 0; k < 13; ++k) sim[k] = 0.f;
    for (int c = 0; c < 128; ++c) {
        float qc = qs[c];
        const float* kr = knT + c * 800 + lane;
#pragma unroll
        for (int k = 0; k < 13; ++k) {
            int m = lane + (k << 6);
            if (m < 800) sim[k] += qc * kr[k << 6];
        }
    }
#pragma unroll
    for (int k = 0; k < 13; ++k)
        if (lane + (k << 6) >= 800) sim[k] = NEG_INF;

    float topv[11]; int topm[11];
#pragma unroll
    for (int t = 0; t < 11; ++t) {
        float bvv = NEG_INF; int bm = 0x7fffffff;
#pragma unroll
        for (int k = 0; k < 13; ++k) {
            if (sim[k] > bvv) { bvv = sim[k]; bm = lane + (k << 6); }
        }
#pragma unroll
        for (int off = 32; off > 0; off >>= 1) {
            float ov = __shfl_xor(bvv, off);
            int om = __shfl_xor(bm, off);
            if (ov > bvv || (ov == bvv && om < bm)) { bvv = ov; bm = om; }
        }
        topv[t] = bvv; topm[t] = bm;
        if ((bm & 63) == lane) {
            int kk = bm >> 6;
#pragma unroll
            for (int k = 0; k < 13; ++k)
                if (k == kk) sim[k] = NEG_INF;
        }
    }
    if (topv[9] - topv[10] < 1e-4f) {
        double s9 = 0.0, s10 = 0.0;
        for (int c = 0; c < 128; ++c) {
            double qc = (double)qs[c];
            s9  += qc * (double)knT[c * 800 + topm[9]];
            s10 += qc * (double)knT[c * 800 + topm[10]];
        }
        if ((s10 > s9) || (s10 == s9 && topm[10] < topm[9])) {
            topv[9] = topv[10]; topm[9] = topm[10];
        }
    }
    float mx = topv[0];
    float e[10], ssum = 0.f;
#pragma unroll
    for (int t = 0; t < 10; ++t) { e[t] = expf(topv[t] - mx); ssum += e[t]; }
    float inv = 1.0f / ssum;
    float o0 = 0.f, o1 = 0.f;
#pragma unroll
    for (int t = 0; t < 10; ++t) {
        float wt = e[t] * inv;
        const float* vr = values + (size_t)topm[t] * 128;
        o0 += wt * vr[lane];
        o1 += wt * vr[lane + 64];
    }
    float* ob = dcat + ((size_t)b * 256) * 4096 + p;
    ob[(size_t)lane * 4096] = o0;
    ob[(size_t)(lane + 64) * 4096] = o1;
}

// ---------------- constant fill for out-of-region center matches ----------------
__global__ void fill_c0_k(const float* __restrict__ c0, float* __restrict__ dcat) {
    int idx = blockIdx.x * 256 + threadIdx.x;
    int p = idx & 4095;
    int c = (idx >> 12) & 127;
    int b = idx >> 19;
    int h = p >> 6, ww = p & 63;
    if (h >= 23 && h <= 40 && ww >= 23 && ww <= 40) return;
    dcat[((size_t)b * 256 + c) * 4096 + p] = c0[c];
}

// ---------------- skip matching v3: block = 64 queries, 32-row key chunks, 50.2 KB LDS ----------------
__global__ void __launch_bounds__(256) match_skip_v3(
        const float* __restrict__ zs,    // (16,128,64,64)
        const float* __restrict__ hn,    // (800,128) normalized
        const float* __restrict__ hard,  // (800,128) raw
        float* __restrict__ dcat) {      // ch 128..255
    __shared__ float sh[12800];          // 51.2 KB: shq[64*132] | max(shh[32*132], red[64*17*4])
    float* shq = sh;
    float* shh = sh + 8448;
    int b = blockIdx.x >> 6, pt = blockIdx.x & 63;
    int pbase = pt * 64;
    int tid = threadIdx.x;

    // stage raw q tile (64 queries x 128 ch), rows padded to 132
    for (int f = tid; f < 8192; f += 256) {
        int c = f >> 6, p = f & 63;
        shq[p * 132 + c] = zs[((size_t)b * 128 + c) * 4096 + pbase + p];
    }

    int qs = tid >> 4, ms = tid & 15;
    float v1[4], v2[4]; int i1[4], i2[4];
#pragma unroll
    for (int u = 0; u < 4; ++u) { v1[u] = NEG_INF; v2[u] = NEG_INF; i1[u] = 0x7fffffff; i2[u] = 0x7fffffff; }

    for (int chunk = 0; chunk < 25; ++chunk) {
        int mbase = chunk * 32;
        __syncthreads();
        for (int f = tid; f < 4096; f += 256) {
            int row = f >> 7, c = f & 127;
            shh[row * 132 + c] = hn[(size_t)(mbase + row) * 128 + c];
        }
        __syncthreads();
        float s[4][2];
#pragma unroll
        for (int u = 0; u < 4; ++u)
#pragma unroll
            for (int j = 0; j < 2; ++j) s[u][j] = 0.f;
        for (int c4 = 0; c4 < 32; ++c4) {
            float4 qv[4], hv[2];
#pragma unroll
            for (int u = 0; u < 4; ++u)
                qv[u] = *(const float4*)(shq + (qs * 4 + u) * 132 + c4 * 4);
#pragma unroll
            for (int j = 0; j < 2; ++j)
                hv[j] = *(const float4*)(shh + (ms + 16 * j) * 132 + c4 * 4);
#pragma unroll
            for (int u = 0; u < 4; ++u)
#pragma unroll
                for (int j = 0; j < 2; ++j)
                    s[u][j] += qv[u].x * hv[j].x + qv[u].y * hv[j].y +
                               qv[u].z * hv[j].z + qv[u].w * hv[j].w;
        }
#pragma unroll
        for (int u = 0; u < 4; ++u)
#pragma unroll
            for (int j = 0; j < 2; ++j) {
                int m = mbase + ms + 16 * j;
                float sv = s[u][j];
                if (sv > v1[u] || (sv == v1[u] && m < i1[u])) {
                    v2[u] = v1[u]; i2[u] = i1[u]; v1[u] = sv; i1[u] = m;
                } else if (sv > v2[u] || (sv == v2[u] && m < i2[u])) {
                    v2[u] = sv; i2[u] = m;
                }
            }
    }
    __syncthreads();
    float4* red = (float4*)(sh + 8448);  // [64 q][17 slots] = 4352 floats
#pragma unroll
    for (int u = 0; u < 4; ++u)
        red[(qs * 4 + u) * 17 + ms] =
            make_float4(v1[u], v2[u], __int_as_float(i1[u]), __int_as_float(i2[u]));
    __syncthreads();
    if (tid < 64) {
        int q = tid;
        float V1 = NEG_INF, V2 = NEG_INF; int I1 = 0x7fffffff, I2 = 0x7fffffff;
        for (int k = 0; k < 16; ++k) {
            float4 e = red[q * 17 + k];
            float cv[2] = { e.x, e.y };
            int ci_[2] = { __float_as_int(e.z), __float_as_int(e.w) };
#pragma unroll
            for (int t = 0; t < 2; ++t) {
                float v = cv[t]; int i = ci_[t];
                if (v > V1 || (v == V1 && i < I1)) { V2 = V1; I2 = I1; V1 = v; I1 = i; }
                else if (v > V2 || (v == V2 && i < I2)) { V2 = v; I2 = i; }
            }
        }
        float qn2 = 0.f;
        for (int c = 0; c < 128; ++c) { float qc = shq[q * 132 + c]; qn2 += qc * qc; }
        float tau = 1e-4f * sqrtf(qn2) + 1e-12f;
        int bi = I1;
        if (V1 - V2 < tau && I2 != 0x7fffffff) {
            double d1 = 0.0, d2 = 0.0;
            const float* h1 = hn + (size_t)I1 * 128;
            const float* h2 = hn + (size_t)I2 * 128;
            for (int c = 0; c < 128; ++c) {
                double qc = (double)shq[q * 132 + c];
                d1 += qc * (double)h1[c];
                d2 += qc * (double)h2[c];
            }
            if ((d2 > d1) || (d2 == d1 && I2 < I1)) bi = I2;
        }
        const float* hr = hard + (size_t)bi * 128;
        float* ob = dcat + ((size_t)b * 256 + 128) * 4096 + pbase + q;
        for (int c = 0; c < 128; ++c) ob[(size_t)c * 4096] = hr[c];
    }
}

// ---------------- decoder conv1 v2: (256->64) 3x3 + relu, LDS input tiles, 32 co ----------------
__global__ void __launch_bounds__(256) dec1_v2(
        const float* __restrict__ dcat, // (16,256,64,64)
        const float* __restrict__ w,    // (64,256,3,3)
        const float* __restrict__ bias,
        float* __restrict__ d1) {       // (16,64,64,64)
    __shared__ float shx[8 * 324];      // 8 ci x 18x18 tile
    int bx = blockIdx.x;                // 16 b * 2 cog * 16 tiles = 512
    int b = bx >> 5, rem = bx & 31;
    int cog = rem >> 4, tile = rem & 15;
    int ph0 = (tile >> 2) * 16, pw0 = (tile & 3) * 16;
    int tid = threadIdx.x;
    int pr = tid >> 4, pc = tid & 15;
    float acc[32];
#pragma unroll
    for (int co = 0; co < 32; ++co) acc[co] = 0.f;
    const float* ib = dcat + (size_t)b * 256 * 4096;

    for (int chunk = 0; chunk < 32; ++chunk) {
        if (chunk) __syncthreads();
        for (int f = tid; f < 2592; f += 256) {
            int ci_l = f / 324, pos = f % 324;
            int r = pos / 18, c = pos % 18;
            int row = ph0 - 1 + r, col = pw0 - 1 + c;
            float v = (row >= 0 && row < 64 && col >= 0 && col < 64)
                          ? ib[((size_t)(chunk * 8 + ci_l)) * 4096 + row * 64 + col] : 0.f;
            shx[f] = v;
        }
        __syncthreads();
#pragma unroll 2
        for (int ci_l = 0; ci_l < 8; ++ci_l) {
            float x9[3][3];
#pragma unroll
            for (int dr = 0; dr < 3; ++dr)
#pragma unroll
                for (int dc = 0; dc < 3; ++dc)
                    x9[dr][dc] = shx[ci_l * 324 + (pr + dr) * 18 + (pc + dc)];
            int ci = chunk * 8 + ci_l;
#pragma unroll
            for (int co = 0; co < 32; ++co) {
                const float* w9 = w + ((size_t)(cog * 32 + co) * 256 + ci) * 9;
                acc[co] += x9[0][0] * w9[0] + x9[0][1] * w9[1] + x9[0][2] * w9[2] +
                           x9[1][0] * w9[3] + x9[1][1] * w9[4] + x9[1][2] * w9[5] +
                           x9[2][0] * w9[6] + x9[2][1] * w9[7] + x9[2][2] * w9[8];
            }
        }
    }
    int ph = ph0 + pr, pw = pw0 + pc;
#pragma unroll
    for (int co = 0; co < 32; ++co) {
        float v = acc[co] + bias[cog * 32 + co];
        d1[((size_t)b * 64 + cog * 32 + co) * 4096 + ph * 64 + pw] = fmaxf(v, 0.f);
    }
}

// ---------------- transposed conv v2: quad-parity, 16 co per thread ----------------
template <int CIN, int COUT, int COG, int H>
__global__ void __launch_bounds__(256) tconv_v2(
        const float* __restrict__ x,   // (16,CIN,H,H)
        const float* __restrict__ w,   // (CIN,COUT,4,4)
        const float* __restrict__ bias,
        float* __restrict__ out) {     // (16,COUT,2H,2H)
    constexpr int NCOG = COUT / COG;
    constexpr int TPS = H / 16;           // quad tiles per side
    constexpr int TILES = TPS * TPS;
    constexpr int HO = 2 * H;
    int bx = blockIdx.x;                  // 16 * NCOG * TILES
    int b = bx / (NCOG * TILES), rem = bx % (NCOG * TILES);
    int cog = rem / TILES, tile = rem % TILES;
    int ti = tile / TPS, tj = tile % TPS;
    int tid = threadIdx.x;
    int i = ti * 16 + (tid >> 4);
    int j = tj * 16 + (tid & 15);

    float acc[2][2][COG];
#pragma unroll
    for (int pr = 0; pr < 2; ++pr)
#pragma unroll
        for (int pc = 0; pc < 2; ++pc)
#pragma unroll
            for (int co = 0; co < COG; ++co) acc[pr][pc][co] = 0.f;

    const float* xb = x + (size_t)b * CIN * H * H;
    for (int ci = 0; ci < CIN; ++ci) {
        const float* xp = xb + (size_t)ci * H * H;
        float xr[3][3];
#pragma unroll
        for (int dr = 0; dr < 3; ++dr) {
            int gr = i - 1 + dr;
            bool vr = (gr >= 0 && gr < H);
#pragma unroll
            for (int dc = 0; dc < 3; ++dc) {
                int gc = j - 1 + dc;
                xr[dr][dc] = (vr && gc >= 0 && gc < H) ? xp[gr * H + gc] : 0.f;
            }
        }
#pragma unroll
        for (int co = 0; co < COG; ++co) {
            const float* wp = w + (((size_t)ci * COUT + cog * COG + co) << 4);
            float wr[16];
#pragma unroll
            for (int k = 0; k < 16; ++k) wr[k] = wp[k];
#pragma unroll
            for (int pr = 0; pr < 2; ++pr)
#pragma unroll
                for (int a = 0; a < 2; ++a)
#pragma unroll
                    for (int pc = 0; pc < 2; ++pc)
#pragma unroll
                        for (int bb = 0; bb < 2; ++bb)
                            acc[pr][pc][co] += xr[pr + a][pc + bb] *
                                               wr[(3 - pr - 2 * a) * 4 + (3 - pc - 2 * bb)];
        }
    }
#pragma unroll
    for (int co = 0; co < COG; ++co) {
        float bv = bias[cog * COG + co];
        float* ob = out + ((size_t)b * COUT + cog * COG + co) * HO * HO;
#pragma unroll
        for (int pr = 0; pr < 2; ++pr)
#pragma unroll
            for (int pc = 0; pc < 2; ++pc)
                ob[(2 * i + pr) * HO + 2 * j + pc] = fmaxf(acc[pr][pc][co] + bv, 0.f);
    }
}

// ---------------- final conv (16->1) 3x3, 4 px per thread ----------------
__global__ void final_v2(const float* __restrict__ t2,  // (16,16,256,256)
                         const float* __restrict__ w,   // (1,16,3,3)
                         const float* __restrict__ bias,
                         float* __restrict__ out) {     // (16,1,256,256)
    int g = blockIdx.x * 256 + threadIdx.x;   // 262144 threads
    int pxb = g * 4;
    int b = pxb >> 16, p = pxb & 65535;
    int h = p >> 8, c0 = p & 255;
    const float* tb = t2 + (size_t)b * 16 * 65536;
    float acc[4];
    float bv = bias[0];
#pragma unroll
    for (int t = 0; t < 4; ++t) acc[t] = bv;
    for (int ci = 0; ci < 16; ++ci) {
        const float* pp = tb + (size_t)ci * 65536;
        const float* w9 = w + ci * 9;
        float win[3][6];
#pragma unroll
        for (int dr = 0; dr < 3; ++dr) {
            int rr = h - 1 + dr;
            bool vr = (rr >= 0 && rr < 256);
#pragma unroll
            for (int dc = 0; dc < 6; ++dc) {
                int cc = c0 - 1 + dc;
                win[dr][dc] = (vr && cc >= 0 && cc < 256) ? pp[rr * 256 + cc] : 0.f;
            }
        }
#pragma unroll
        for (int t = 0; t < 4; ++t)
#pragma unroll
            for (int dr = 0; dr < 3; ++dr)
#pragma unroll
                for (int dc = 0; dc < 3; ++dc)
                    acc[t] += win[dr][t + dc] * w9[dr * 3 + dc];
    }
    *(float4*)(out + pxb) = make_float4(acc[0], acc[1], acc[2], acc[3]);
}

// ---------------- launch ----------------
extern "C" void kernel_launch(void* const* d_in, const int* in_sizes, int n_in,
                              void* d_out, int out_size, void* d_ws, size_t ws_size,
                              hipStream_t stream) {
    (void)in_sizes; (void)n_in; (void)out_size; (void)ws_size;
    const float* x     = (const float*)d_in[0];
    const float* cw1   = (const float*)d_in[1];
    const float* cb1   = (const float*)d_in[2];
    const float* cw2   = (const float*)d_in[3];
    const float* cb2   = (const float*)d_in[4];
    const float* sw1   = (const float*)d_in[5];
    const float* sb1   = (const float*)d_in[6];
    const float* sw2   = (const float*)d_in[7];
    const float* sb2   = (const float*)d_in[8];
    const float* mkeys = (const float*)d_in[9];
    const float* mvals = (const float*)d_in[10];
    const float* mhard = (const float*)d_in[11];
    const float* dw1   = (const float*)d_in[12];
    const float* db1   = (const float*)d_in[13];
    const float* tw1   = (const float*)d_in[14];
    const float* tb1   = (const float*)d_in[15];
    const float* tw2   = (const float*)d_in[16];
    const float* tb2   = (const float*)d_in[17];
    const float* dw2   = (const float*)d_in[18];
    const float* db2   = (const float*)d_in[19];
    float* out = (float*)d_out;
    float* ws  = (float*)d_ws;

    const size_t OFF_KN  = 0;                   // knT: 128*800
    const size_t OFF_HN  = 102400;              // hn:  800*128
    const size_t OFF_C0  = 204800;              // c0:  128
    const size_t OFF_R14 = 204928;              // zc1 -> zs -> t1
    const size_t OFF_R2  = OFF_R14 + 8388608;   // zc
    const size_t OFF_R3  = OFF_R2 + 8388608;    // zs1 -> d1
    const size_t OFF_R5  = OFF_R3 + 4194304;    // dcat -> t2

    float* knT  = ws + OFF_KN;
    float* hn   = ws + OFF_HN;
    float* c0   = ws + OFF_C0;
    float* zc1  = ws + OFF_R14;
    float* zs   = ws + OFF_R14;
    float* t1   = ws + OFF_R14;
    float* zc   = ws + OFF_R2;
    float* zs1  = ws + OFF_R3;
    float* d1b  = ws + OFF_R3;
    float* dcat = ws + OFF_R5;
    float* t2   = ws + OFF_R5;

    prep_norm_k<<<800, 128, 0, stream>>>(mkeys, mhard, knT, hn);
    prep_c0_k<<<1, 128, 0, stream>>>(mvals, c0);

    ce1_k<<<16 * 2 * 6, 256, 0, stream>>>(x, cw1, cb1, zc1);
    se1_k<<<16 * 64, 256, 0, stream>>>(x, sw1, sb1, zs1);
    ce2_k<<<16 * 128, 256, 0, stream>>>(zc1, cw2, cb2, zc);
    se2_v2<<<16 * 16 * 16, 256, 0, stream>>>(zs1, sw2, sb2, zs);  // overwrites zc1 (dead)

    match_center_k<<<16 * 324, 64, 0, stream>>>(zc, knT, mvals, dcat);
    fill_c0_k<<<32768, 256, 0, stream>>>(c0, dcat);
    match_skip_v3<<<16 * 64, 256, 0, stream>>>(zs, hn, mhard, dcat);

    dec1_v2<<<16 * 2 * 16, 256, 0, stream>>>(dcat, dw1, db1, d1b);          // overwrites zs1 (dead)
    tconv_v2<64, 32, 16, 64><<<16 * 2 * 16, 256, 0, stream>>>(d1b, tw1, tb1, t1);   // overwrites zs (dead)
    tconv_v2<32, 16, 16, 128><<<16 * 1 * 64, 256, 0, stream>>>(t1, tw2, tb2, t2);   // overwrites dcat (dead)
    final_v2<<<1024, 256, 0, stream>>>(t2, dw2, db2, out);  // 4 px/thread, 1M px total
}

// Round 4
// 2186.642 us; speedup vs baseline: 3.8824x; 1.3707x over previous
//
#include <hip/hip_runtime.h>
#include <cstdint>
#include <cstddef>

#define NEG_INF (-3.0e38f)

// ---------------- prep: normalize keys (transposed) + hard (row-major) ----------------
__global__ void prep_norm_k(const float* __restrict__ keys,
                            const float* __restrict__ hard,
                            float* __restrict__ knT,   // [128][800]
                            float* __restrict__ hn) {  // [800][128]
    int m = blockIdx.x;      // 0..799
    int c = threadIdx.x;     // 0..127
    float kv = keys[m * 128 + c];
    float hv = hard[m * 128 + c];
    __shared__ float s1[128];
    __shared__ float s2[128];
    s1[c] = kv * kv;
    s2[c] = hv * hv;
    __syncthreads();
    for (int off = 64; off > 0; off >>= 1) {
        if (c < off) { s1[c] += s1[c + off]; s2[c] += s2[c + off]; }
        __syncthreads();
    }
    float ks = 1.0f / fmaxf(sqrtf(s1[0]), 1e-12f);
    float hs = 1.0f / fmaxf(sqrtf(s2[0]), 1e-12f);
    knT[c * 800 + m] = kv * ks;
    hn[m * 128 + c]  = hv * hs;
}

__global__ void prep_c0_k(const float* __restrict__ values, float* __restrict__ c0) {
    int c = threadIdx.x;  // 128 threads
    float s = 0.f;
    for (int m = 0; m < 10; ++m) s += values[m * 128 + c];
    c0[c] = s * 0.1f;
}

// ---------------- center conv1+pool: only pooled rect [45,83)^2, 16 co per block ----------------
__global__ void ce1_k(const float* __restrict__ x,   // (16,1,256,256)
                      const float* __restrict__ w,   // (32,1,3,3)
                      const float* __restrict__ bias,
                      float* __restrict__ out) {     // (16,32,128,128) rect only
    int bx = blockIdx.x;            // 16 b * 2 cog * 6 tiles
    int b = bx / 12, rem = bx % 12;
    int cog = rem / 6, tile = rem % 6;
    int idx = tile * 256 + threadIdx.x;
    if (idx >= 1444) return;
    int ph = 45 + idx / 38, pw = 45 + idx % 38;
    const float* xb = x + (size_t)b * 65536;
    float win[4][4];
#pragma unroll
    for (int r = 0; r < 4; ++r) {
        int ih = 2 * ph - 1 + r;
        bool vr = (ih >= 96 && ih < 160);
#pragma unroll
        for (int c = 0; c < 4; ++c) {
            int iw = 2 * pw - 1 + c;
            win[r][c] = (vr && iw >= 96 && iw < 160) ? xb[ih * 256 + iw] : 0.f;
        }
    }
#pragma unroll
    for (int co8 = 0; co8 < 16; ++co8) {
        int co = cog * 16 + co8;
        const float* w9 = w + co * 9;
        float bv = bias[co];
        float a00 = bv, a01 = bv, a10 = bv, a11 = bv;
#pragma unroll
        for (int kh = 0; kh < 3; ++kh)
#pragma unroll
            for (int kw = 0; kw < 3; ++kw) {
                float wv = w9[kh * 3 + kw];
                a00 += win[kh][kw] * wv;
                a01 += win[kh][kw + 1] * wv;
                a10 += win[kh + 1][kw] * wv;
                a11 += win[kh + 1][kw + 1] * wv;
            }
        float mx = fmaxf(fmaxf(a00, a01), fmaxf(a10, a11));
        out[((size_t)b * 32 + co) * 16384 + ph * 128 + pw] = fmaxf(mx, 0.f);
    }
}

// ---------------- skip conv1+pool: full, 16 co per thread ----------------
__global__ void se1_k(const float* __restrict__ x,   // (16,1,256,256)
                      const float* __restrict__ w,   // (16,1,3,3)
                      const float* __restrict__ bias,
                      float* __restrict__ out) {     // (16,16,128,128)
    int bx = blockIdx.x;            // 16 b * 64 tiles
    int b = bx >> 6, tile = bx & 63;
    int idx = tile * 256 + threadIdx.x;   // 0..16383
    int ph = idx >> 7, pw = idx & 127;
    const float* xb = x + (size_t)b * 65536;
    float win[4][4];
#pragma unroll
    for (int r = 0; r < 4; ++r) {
        int ih = 2 * ph - 1 + r;
        bool vr = (ih >= 0 && ih < 256);
#pragma unroll
        for (int c = 0; c < 4; ++c) {
            int iw = 2 * pw - 1 + c;
            win[r][c] = (vr && iw >= 0 && iw < 256) ? xb[ih * 256 + iw] : 0.f;
        }
    }
#pragma unroll
    for (int co = 0; co < 16; ++co) {
        const float* w9 = w + co * 9;
        float bv = bias[co];
        float a00 = bv, a01 = bv, a10 = bv, a11 = bv;
#pragma unroll
        for (int kh = 0; kh < 3; ++kh)
#pragma unroll
            for (int kw = 0; kw < 3; ++kw) {
                float wv = w9[kh * 3 + kw];
                a00 += win[kh][kw] * wv;
                a01 += win[kh][kw + 1] * wv;
                a10 += win[kh + 1][kw] * wv;
                a11 += win[kh + 1][kw + 1] * wv;
            }
        float mx = fmaxf(fmaxf(a00, a01), fmaxf(a10, a11));
        out[((size_t)b * 16 + co) * 16384 + idx] = fmaxf(mx, 0.f);
    }
}

// ---------------- center conv2 v3 (32->128) + relu + pool, region only, 8 co/thread ----------------
__global__ void __launch_bounds__(256) ce2_v3(
        const float* __restrict__ zc1,  // (16,32,128,128)
        const float* __restrict__ w,    // (128,32,3,3)
        const float* __restrict__ bias,
        float* __restrict__ zc) {       // (16,128,64,64) region only
    int bx = blockIdx.x;                // 16 b * 16 cog
    int b = bx >> 4, cog = bx & 15;
    const float* ib = zc1 + (size_t)b * 32 * 16384;
    for (int px = threadIdx.x; px < 324; px += 256) {
        int h = 23 + px / 18, ww = 23 + px % 18;
        float acc[8][4];
#pragma unroll
        for (int c8 = 0; c8 < 8; ++c8)
#pragma unroll
            for (int t = 0; t < 4; ++t) acc[c8][t] = 0.f;
        for (int ci = 0; ci < 32; ++ci) {
            // rows 45..82, cols 45..82 — interior, no guards needed
            const float* p = ib + ci * 16384 + (2 * h - 1) * 128 + (2 * ww - 1);
            float win[4][4];
#pragma unroll
            for (int r = 0; r < 4; ++r)
#pragma unroll
                for (int s = 0; s < 4; ++s) win[r][s] = p[r * 128 + s];
#pragma unroll
            for (int c8 = 0; c8 < 8; ++c8) {
                const float* w9 = w + ((size_t)(cog * 8 + c8) * 32 + ci) * 9;
#pragma unroll
                for (int kh = 0; kh < 3; ++kh)
#pragma unroll
                    for (int kw = 0; kw < 3; ++kw) {
                        float wv = w9[kh * 3 + kw];
                        acc[c8][0] += win[kh][kw] * wv;
                        acc[c8][1] += win[kh][kw + 1] * wv;
                        acc[c8][2] += win[kh + 1][kw] * wv;
                        acc[c8][3] += win[kh + 1][kw + 1] * wv;
                    }
            }
        }
#pragma unroll
        for (int c8 = 0; c8 < 8; ++c8) {
            int co = cog * 8 + c8;
            float mx = fmaxf(fmaxf(acc[c8][0], acc[c8][1]), fmaxf(acc[c8][2], acc[c8][3])) + bias[co];
            zc[((size_t)b * 128 + co) * 4096 + h * 64 + ww] = fmaxf(mx, 0.f);
        }
    }
}

// ---------------- skip conv2 (16->128) + relu + pool, 8 co per thread ----------------
__global__ void se2_v2(const float* __restrict__ zs1,  // (16,16,128,128)
                       const float* __restrict__ w,    // (128,16,3,3)
                       const float* __restrict__ bias,
                       float* __restrict__ zs) {       // (16,128,64,64)
    int bx = blockIdx.x;            // 16 b * 16 cog * 16 tiles = 4096
    int b = bx >> 8, rem = bx & 255;
    int cog = rem >> 4, tile = rem & 15;
    int px = tile * 256 + threadIdx.x;  // 0..4095
    int ph = px >> 6, pw = px & 63;
    const float* ib = zs1 + (size_t)b * 16 * 16384;
    float acc[8][4];
#pragma unroll
    for (int c8 = 0; c8 < 8; ++c8)
#pragma unroll
        for (int t = 0; t < 4; ++t) acc[c8][t] = 0.f;
    for (int ci = 0; ci < 16; ++ci) {
        const float* p = ib + ci * 16384;
        float win[4][4];
#pragma unroll
        for (int r = 0; r < 4; ++r) {
            int rr = 2 * ph - 1 + r;
            bool vr = (rr >= 0 && rr < 128);
#pragma unroll
            for (int s = 0; s < 4; ++s) {
                int cc = 2 * pw - 1 + s;
                win[r][s] = (vr && cc >= 0 && cc < 128) ? p[rr * 128 + cc] : 0.f;
            }
        }
#pragma unroll
        for (int c8 = 0; c8 < 8; ++c8) {
            const float* w9 = w + ((size_t)(cog * 8 + c8) * 16 + ci) * 9;
#pragma unroll
            for (int kh = 0; kh < 3; ++kh)
#pragma unroll
                for (int kw = 0; kw < 3; ++kw) {
                    float wv = w9[kh * 3 + kw];
                    acc[c8][0] += win[kh][kw] * wv;
                    acc[c8][1] += win[kh][kw + 1] * wv;
                    acc[c8][2] += win[kh + 1][kw] * wv;
                    acc[c8][3] += win[kh + 1][kw + 1] * wv;
                }
        }
    }
#pragma unroll
    for (int c8 = 0; c8 < 8; ++c8) {
        int co = cog * 8 + c8;
        float bv = bias[co];
        float mx = fmaxf(fmaxf(acc[c8][0], acc[c8][1]), fmaxf(acc[c8][2], acc[c8][3])) + bv;
        zs[((size_t)b * 128 + co) * 4096 + px] = fmaxf(mx, 0.f);
    }
}

// ---------------- center matching: one wave per in-region query ----------------
__global__ void __launch_bounds__(64) match_center_k(
        const float* __restrict__ zc,     // (16,128,64,64)
        const float* __restrict__ knT,    // [128][800] normalized
        const float* __restrict__ values, // (800,128)
        float* __restrict__ dcat) {       // (16,256,64,64), ch 0..127
    int bq = blockIdx.x;
    int b = bq / 324, q = bq % 324;
    int h = 23 + q / 18, ww = 23 + q % 18;
    int p = h * 64 + ww;
    int lane = threadIdx.x;
    __shared__ float qs[128];
    const float* zb = zc + ((size_t)b * 128) * 4096 + p;
    float v0 = zb[(size_t)lane * 4096];
    float v1 = zb[(size_t)(lane + 64) * 4096];
    float ss = v0 * v0 + v1 * v1;
#pragma unroll
    for (int off = 32; off > 0; off >>= 1) ss += __shfl_xor(ss, off);
    float sc = 1.0f / fmaxf(sqrtf(ss), 1e-12f);
    qs[lane] = v0 * sc;
    qs[lane + 64] = v1 * sc;
    __syncthreads();

    float sim[13];
#pragma unroll
    for (int k = 0; k < 13; ++k) sim[k] = 0.f;
    for (int c = 0; c < 128; ++c) {
        float qc = qs[c];
        const float* kr = knT + c * 800 + lane;
#pragma unroll
        for (int k = 0; k < 13; ++k) {
            int m = lane + (k << 6);
            if (m < 800) sim[k] += qc * kr[k << 6];
        }
    }
#pragma unroll
    for (int k = 0; k < 13; ++k)
        if (lane + (k << 6) >= 800) sim[k] = NEG_INF;

    float topv[11]; int topm[11];
#pragma unroll
    for (int t = 0; t < 11; ++t) {
        float bvv = NEG_INF; int bm = 0x7fffffff;
#pragma unroll
        for (int k = 0; k < 13; ++k) {
            if (sim[k] > bvv) { bvv = sim[k]; bm = lane + (k << 6); }
        }
#pragma unroll
        for (int off = 32; off > 0; off >>= 1) {
            float ov = __shfl_xor(bvv, off);
            int om = __shfl_xor(bm, off);
            if (ov > bvv || (ov == bvv && om < bm)) { bvv = ov; bm = om; }
        }
        topv[t] = bvv; topm[t] = bm;
        if ((bm & 63) == lane) {
            int kk = bm >> 6;
#pragma unroll
            for (int k = 0; k < 13; ++k)
                if (k == kk) sim[k] = NEG_INF;
        }
    }
    if (topv[9] - topv[10] < 1e-4f) {
        double s9 = 0.0, s10 = 0.0;
        for (int c = 0; c < 128; ++c) {
            double qc = (double)qs[c];
            s9  += qc * (double)knT[c * 800 + topm[9]];
            s10 += qc * (double)knT[c * 800 + topm[10]];
        }
        if ((s10 > s9) || (s10 == s9 && topm[10] < topm[9])) {
            topv[9] = topv[10]; topm[9] = topm[10];
        }
    }
    float mx = topv[0];
    float e[10], ssum = 0.f;
#pragma unroll
    for (int t = 0; t < 10; ++t) { e[t] = expf(topv[t] - mx); ssum += e[t]; }
    float inv = 1.0f / ssum;
    float o0 = 0.f, o1 = 0.f;
#pragma unroll
    for (int t = 0; t < 10; ++t) {
        float wt = e[t] * inv;
        const float* vr = values + (size_t)topm[t] * 128;
        o0 += wt * vr[lane];
        o1 += wt * vr[lane + 64];
    }
    float* ob = dcat + ((size_t)b * 256) * 4096 + p;
    ob[(size_t)lane * 4096] = o0;
    ob[(size_t)(lane + 64) * 4096] = o1;
}

// ---------------- constant fill for out-of-region center matches ----------------
__global__ void fill_c0_k(const float* __restrict__ c0, float* __restrict__ dcat) {
    int idx = blockIdx.x * 256 + threadIdx.x;
    int p = idx & 4095;
    int c = (idx >> 12) & 127;
    int b = idx >> 19;
    int h = p >> 6, ww = p & 63;
    if (h >= 23 && h <= 40 && ww >= 23 && ww <= 40) return;
    dcat[((size_t)b * 256 + c) * 4096 + p] = c0[c];
}

// ---------------- skip matching v3: block = 64 queries, 32-row key chunks, 50.2 KB LDS ----------------
__global__ void __launch_bounds__(256) match_skip_v3(
        const float* __restrict__ zs,    // (16,128,64,64)
        const float* __restrict__ hn,    // (800,128) normalized
        const float* __restrict__ hard,  // (800,128) raw
        float* __restrict__ dcat) {      // ch 128..255
    __shared__ float sh[12800];          // 51.2 KB: shq[64*132] | max(shh[32*132], red[64*17*4])
    float* shq = sh;
    float* shh = sh + 8448;
    int b = blockIdx.x >> 6, pt = blockIdx.x & 63;
    int pbase = pt * 64;
    int tid = threadIdx.x;

    for (int f = tid; f < 8192; f += 256) {
        int c = f >> 6, p = f & 63;
        shq[p * 132 + c] = zs[((size_t)b * 128 + c) * 4096 + pbase + p];
    }

    int qs = tid >> 4, ms = tid & 15;
    float v1[4], v2[4]; int i1[4], i2[4];
#pragma unroll
    for (int u = 0; u < 4; ++u) { v1[u] = NEG_INF; v2[u] = NEG_INF; i1[u] = 0x7fffffff; i2[u] = 0x7fffffff; }

    for (int chunk = 0; chunk < 25; ++chunk) {
        int mbase = chunk * 32;
        __syncthreads();
        for (int f = tid; f < 4096; f += 256) {
            int row = f >> 7, c = f & 127;
            shh[row * 132 + c] = hn[(size_t)(mbase + row) * 128 + c];
        }
        __syncthreads();
        float s[4][2];
#pragma unroll
        for (int u = 0; u < 4; ++u)
#pragma unroll
            for (int j = 0; j < 2; ++j) s[u][j] = 0.f;
        for (int c4 = 0; c4 < 32; ++c4) {
            float4 qv[4], hv[2];
#pragma unroll
            for (int u = 0; u < 4; ++u)
                qv[u] = *(const float4*)(shq + (qs * 4 + u) * 132 + c4 * 4);
#pragma unroll
            for (int j = 0; j < 2; ++j)
                hv[j] = *(const float4*)(shh + (ms + 16 * j) * 132 + c4 * 4);
#pragma unroll
            for (int u = 0; u < 4; ++u)
#pragma unroll
                for (int j = 0; j < 2; ++j)
                    s[u][j] += qv[u].x * hv[j].x + qv[u].y * hv[j].y +
                               qv[u].z * hv[j].z + qv[u].w * hv[j].w;
        }
#pragma unroll
        for (int u = 0; u < 4; ++u)
#pragma unroll
            for (int j = 0; j < 2; ++j) {
                int m = mbase + ms + 16 * j;
                float sv = s[u][j];
                if (sv > v1[u] || (sv == v1[u] && m < i1[u])) {
                    v2[u] = v1[u]; i2[u] = i1[u]; v1[u] = sv; i1[u] = m;
                } else if (sv > v2[u] || (sv == v2[u] && m < i2[u])) {
                    v2[u] = sv; i2[u] = m;
                }
            }
    }
    __syncthreads();
    float4* red = (float4*)(sh + 8448);  // [64 q][17 slots] = 4352 floats
#pragma unroll
    for (int u = 0; u < 4; ++u)
        red[(qs * 4 + u) * 17 + ms] =
            make_float4(v1[u], v2[u], __int_as_float(i1[u]), __int_as_float(i2[u]));
    __syncthreads();
    if (tid < 64) {
        int q = tid;
        float V1 = NEG_INF, V2 = NEG_INF; int I1 = 0x7fffffff, I2 = 0x7fffffff;
        for (int k = 0; k < 16; ++k) {
            float4 e = red[q * 17 + k];
            float cv[2] = { e.x, e.y };
            int ci_[2] = { __float_as_int(e.z), __float_as_int(e.w) };
#pragma unroll
            for (int t = 0; t < 2; ++t) {
                float v = cv[t]; int i = ci_[t];
                if (v > V1 || (v == V1 && i < I1)) { V2 = V1; I2 = I1; V1 = v; I1 = i; }
                else if (v > V2 || (v == V2 && i < I2)) { V2 = v; I2 = i; }
            }
        }
        float qn2 = 0.f;
        for (int c = 0; c < 128; ++c) { float qc = shq[q * 132 + c]; qn2 += qc * qc; }
        float tau = 1e-4f * sqrtf(qn2) + 1e-12f;
        int bi = I1;
        if (V1 - V2 < tau && I2 != 0x7fffffff) {
            double d1 = 0.0, d2 = 0.0;
            const float* h1 = hn + (size_t)I1 * 128;
            const float* h2 = hn + (size_t)I2 * 128;
            for (int c = 0; c < 128; ++c) {
                double qc = (double)shq[q * 132 + c];
                d1 += qc * (double)h1[c];
                d2 += qc * (double)h2[c];
            }
            if ((d2 > d1) || (d2 == d1 && I2 < I1)) bi = I2;
        }
        const float* hr = hard + (size_t)bi * 128;
        float* ob = dcat + ((size_t)b * 256 + 128) * 4096 + pbase + q;
        for (int c = 0; c < 128; ++c) ob[(size_t)c * 4096] = hr[c];
    }
}

// ---------------- decoder conv1 v3: (256->64) 3x3 + relu, double-buffered LDS, 16 co ----------------
__global__ void __launch_bounds__(256) dec1_v3(
        const float* __restrict__ dcat, // (16,256,64,64)
        const float* __restrict__ w,    // (64,256,3,3)
        const float* __restrict__ bias,
        float* __restrict__ d1) {       // (16,64,64,64)
    __shared__ float shx[2][8 * 324];   // 2 x 8ci x 18x18 tile = 20.7 KB
    int bx = blockIdx.x;                // 16 b * 4 cog * 16 tiles = 1024
    int b = bx >> 6, rem = bx & 63;
    int cog = rem >> 4, tile = rem & 15;
    int ph0 = (tile >> 2) * 16, pw0 = (tile & 3) * 16;
    int tid = threadIdx.x;
    int pr = tid >> 4, pc = tid & 15;
    float acc[16];
#pragma unroll
    for (int co = 0; co < 16; ++co) acc[co] = 0.f;
    const float* ib = dcat + (size_t)b * 256 * 4096;

    // stage chunk 0
#pragma unroll
    for (int k = 0; k < 11; ++k) {
        int f = tid + k * 256;
        if (f < 2592) {
            int ci_l = f / 324, pos = f % 324;
            int r = pos / 18, c = pos % 18;
            int row = ph0 - 1 + r, col = pw0 - 1 + c;
            shx[0][f] = (row >= 0 && row < 64 && col >= 0 && col < 64)
                            ? ib[(size_t)ci_l * 4096 + row * 64 + col] : 0.f;
        }
    }
    __syncthreads();

    for (int chunk = 0; chunk < 32; ++chunk) {
        int cur = chunk & 1;
        // prefetch next chunk into registers
        float pf[11];
        if (chunk < 31) {
#pragma unroll
            for (int k = 0; k < 11; ++k) {
                int f = tid + k * 256;
                if (f < 2592) {
                    int ci_l = f / 324, pos = f % 324;
                    int r = pos / 18, c = pos % 18;
                    int row = ph0 - 1 + r, col = pw0 - 1 + c;
                    pf[k] = (row >= 0 && row < 64 && col >= 0 && col < 64)
                                ? ib[((size_t)(chunk + 1) * 8 + ci_l) * 4096 + row * 64 + col] : 0.f;
                }
            }
        }
        // compute from current buffer
#pragma unroll 2
        for (int ci_l = 0; ci_l < 8; ++ci_l) {
            float x9[3][3];
#pragma unroll
            for (int dr = 0; dr < 3; ++dr)
#pragma unroll
                for (int dc = 0; dc < 3; ++dc)
                    x9[dr][dc] = shx[cur][ci_l * 324 + (pr + dr) * 18 + (pc + dc)];
            int ci = chunk * 8 + ci_l;
#pragma unroll
            for (int co = 0; co < 16; ++co) {
                const float* w9 = w + ((size_t)(cog * 16 + co) * 256 + ci) * 9;
                acc[co] += x9[0][0] * w9[0] + x9[0][1] * w9[1] + x9[0][2] * w9[2] +
                           x9[1][0] * w9[3] + x9[1][1] * w9[4] + x9[1][2] * w9[5] +
                           x9[2][0] * w9[6] + x9[2][1] * w9[7] + x9[2][2] * w9[8];
            }
        }
        // write prefetched data into the other buffer; one barrier per chunk
        if (chunk < 31) {
#pragma unroll
            for (int k = 0; k < 11; ++k) {
                int f = tid + k * 256;
                if (f < 2592) shx[1 - cur][f] = pf[k];
            }
            __syncthreads();
        }
    }
    int ph = ph0 + pr, pw = pw0 + pc;
#pragma unroll
    for (int co = 0; co < 16; ++co) {
        float v = acc[co] + bias[cog * 16 + co];
        d1[((size_t)b * 64 + cog * 16 + co) * 4096 + ph * 64 + pw] = fmaxf(v, 0.f);
    }
}

// ---------------- transposed conv v2: quad-parity, 16 co per thread ----------------
template <int CIN, int COUT, int COG, int H>
__global__ void __launch_bounds__(256) tconv_v2(
        const float* __restrict__ x,   // (16,CIN,H,H)
        const float* __restrict__ w,   // (CIN,COUT,4,4)
        const float* __restrict__ bias,
        float* __restrict__ out) {     // (16,COUT,2H,2H)
    constexpr int NCOG = COUT / COG;
    constexpr int TPS = H / 16;           // quad tiles per side
    constexpr int TILES = TPS * TPS;
    constexpr int HO = 2 * H;
    int bx = blockIdx.x;                  // 16 * NCOG * TILES
    int b = bx / (NCOG * TILES), rem = bx % (NCOG * TILES);
    int cog = rem / TILES, tile = rem % TILES;
    int ti = tile / TPS, tj = tile % TPS;
    int tid = threadIdx.x;
    int i = ti * 16 + (tid >> 4);
    int j = tj * 16 + (tid & 15);

    float acc[2][2][COG];
#pragma unroll
    for (int pr = 0; pr < 2; ++pr)
#pragma unroll
        for (int pc = 0; pc < 2; ++pc)
#pragma unroll
            for (int co = 0; co < COG; ++co) acc[pr][pc][co] = 0.f;

    const float* xb = x + (size_t)b * CIN * H * H;
    for (int ci = 0; ci < CIN; ++ci) {
        const float* xp = xb + (size_t)ci * H * H;
        float xr[3][3];
#pragma unroll
        for (int dr = 0; dr < 3; ++dr) {
            int gr = i - 1 + dr;
            bool vr = (gr >= 0 && gr < H);
#pragma unroll
            for (int dc = 0; dc < 3; ++dc) {
                int gc = j - 1 + dc;
                xr[dr][dc] = (vr && gc >= 0 && gc < H) ? xp[gr * H + gc] : 0.f;
            }
        }
#pragma unroll
        for (int co = 0; co < COG; ++co) {
            const float* wp = w + (((size_t)ci * COUT + cog * COG + co) << 4);
            float wr[16];
#pragma unroll
            for (int k = 0; k < 16; ++k) wr[k] = wp[k];
#pragma unroll
            for (int pr = 0; pr < 2; ++pr)
#pragma unroll
                for (int a = 0; a < 2; ++a)
#pragma unroll
                    for (int pc = 0; pc < 2; ++pc)
#pragma unroll
                        for (int bb = 0; bb < 2; ++bb)
                            acc[pr][pc][co] += xr[pr + a][pc + bb] *
                                               wr[(3 - pr - 2 * a) * 4 + (3 - pc - 2 * bb)];
        }
    }
#pragma unroll
    for (int co = 0; co < COG; ++co) {
        float bv = bias[cog * COG + co];
        float* ob = out + ((size_t)b * COUT + cog * COG + co) * HO * HO;
#pragma unroll
        for (int pr = 0; pr < 2; ++pr)
#pragma unroll
            for (int pc = 0; pc < 2; ++pc)
                ob[(2 * i + pr) * HO + 2 * j + pc] = fmaxf(acc[pr][pc][co] + bv, 0.f);
    }
}

// ---------------- final conv (16->1) 3x3, 4 px per thread ----------------
__global__ void final_v2(const float* __restrict__ t2,  // (16,16,256,256)
                         const float* __restrict__ w,   // (1,16,3,3)
                         const float* __restrict__ bias,
                         float* __restrict__ out) {     // (16,1,256,256)
    int g = blockIdx.x * 256 + threadIdx.x;   // 262144 threads
    int pxb = g * 4;
    int b = pxb >> 16, p = pxb & 65535;
    int h = p >> 8, c0 = p & 255;
    const float* tb = t2 + (size_t)b * 16 * 65536;
    float acc[4];
    float bv = bias[0];
#pragma unroll
    for (int t = 0; t < 4; ++t) acc[t] = bv;
    for (int ci = 0; ci < 16; ++ci) {
        const float* pp = tb + (size_t)ci * 65536;
        const float* w9 = w + ci * 9;
        float win[3][6];
#pragma unroll
        for (int dr = 0; dr < 3; ++dr) {
            int rr = h - 1 + dr;
            bool vr = (rr >= 0 && rr < 256);
#pragma unroll
            for (int dc = 0; dc < 6; ++dc) {
                int cc = c0 - 1 + dc;
                win[dr][dc] = (vr && cc >= 0 && cc < 256) ? pp[rr * 256 + cc] : 0.f;
            }
        }
#pragma unroll
        for (int t = 0; t < 4; ++t)
#pragma unroll
            for (int dr = 0; dr < 3; ++dr)
#pragma unroll
                for (int dc = 0; dc < 3; ++dc)
                    acc[t] += win[dr][t + dc] * w9[dr * 3 + dc];
    }
    *(float4*)(out + pxb) = make_float4(acc[0], acc[1], acc[2], acc[3]);
}

// ---------------- launch ----------------
extern "C" void kernel_launch(void* const* d_in, const int* in_sizes, int n_in,
                              void* d_out, int out_size, void* d_ws, size_t ws_size,
                              hipStream_t stream) {
    (void)in_sizes; (void)n_in; (void)out_size; (void)ws_size;
    const float* x     = (const float*)d_in[0];
    const float* cw1   = (const float*)d_in[1];
    const float* cb1   = (const float*)d_in[2];
    const float* cw2   = (const float*)d_in[3];
    const float* cb2   = (const float*)d_in[4];
    const float* sw1   = (const float*)d_in[5];
    const float* sb1   = (const float*)d_in[6];
    const float* sw2   = (const float*)d_in[7];
    const float* sb2   = (const float*)d_in[8];
    const float* mkeys = (const float*)d_in[9];
    const float* mvals = (const float*)d_in[10];
    const float* mhard = (const float*)d_in[11];
    const float* dw1   = (const float*)d_in[12];
    const float* db1   = (const float*)d_in[13];
    const float* tw1   = (const float*)d_in[14];
    const float* tb1   = (const float*)d_in[15];
    const float* tw2   = (const float*)d_in[16];
    const float* tb2   = (const float*)d_in[17];
    const float* dw2   = (const float*)d_in[18];
    const float* db2   = (const float*)d_in[19];
    float* out = (float*)d_out;
    float* ws  = (float*)d_ws;

    const size_t OFF_KN  = 0;                   // knT: 128*800
    const size_t OFF_HN  = 102400;              // hn:  800*128
    const size_t OFF_C0  = 204800;              // c0:  128
    const size_t OFF_R14 = 204928;              // zc1 -> zs -> t1
    const size_t OFF_R2  = OFF_R14 + 8388608;   // zc
    const size_t OFF_R3  = OFF_R2 + 8388608;    // zs1 -> d1
    const size_t OFF_R5  = OFF_R3 + 4194304;    // dcat -> t2

    float* knT  = ws + OFF_KN;
    float* hn   = ws + OFF_HN;
    float* c0   = ws + OFF_C0;
    float* zc1  = ws + OFF_R14;
    float* zs   = ws + OFF_R14;
    float* t1   = ws + OFF_R14;
    float* zc   = ws + OFF_R2;
    float* zs1  = ws + OFF_R3;
    float* d1b  = ws + OFF_R3;
    float* dcat = ws + OFF_R5;
    float* t2   = ws + OFF_R5;

    prep_norm_k<<<800, 128, 0, stream>>>(mkeys, mhard, knT, hn);
    prep_c0_k<<<1, 128, 0, stream>>>(mvals, c0);

    ce1_k<<<16 * 2 * 6, 256, 0, stream>>>(x, cw1, cb1, zc1);
    se1_k<<<16 * 64, 256, 0, stream>>>(x, sw1, sb1, zs1);
    ce2_v3<<<16 * 16, 256, 0, stream>>>(zc1, cw2, cb2, zc);
    se2_v2<<<16 * 16 * 16, 256, 0, stream>>>(zs1, sw2, sb2, zs);  // overwrites zc1 (dead)

    match_center_k<<<16 * 324, 64, 0, stream>>>(zc, knT, mvals, dcat);
    fill_c0_k<<<32768, 256, 0, stream>>>(c0, dcat);
    match_skip_v3<<<16 * 64, 256, 0, stream>>>(zs, hn, mhard, dcat);

    dec1_v3<<<16 * 4 * 16, 256, 0, stream>>>(dcat, dw1, db1, d1b);          // overwrites zs1 (dead)
    tconv_v2<64, 32, 16, 64><<<16 * 2 * 16, 256, 0, stream>>>(d1b, tw1, tb1, t1);   // overwrites zs (dead)
    tconv_v2<32, 16, 16, 128><<<16 * 1 * 64, 256, 0, stream>>>(t1, tw2, tb2, t2);   // overwrites dcat (dead)
    final_v2<<<1024, 256, 0, stream>>>(t2, dw2, db2, out);  // 4 px/thread, 1M px total
}

// Round 5
// 1611.443 us; speedup vs baseline: 5.2683x; 1.3569x over previous
//
#include <hip/hip_runtime.h>
#include <cstdint>
#include <cstddef>

#define NEG_INF (-3.0e38f)

// ---------------- prep: normalize keys (transposed) + hard (row-major) ----------------
__global__ void prep_norm_k(const float* __restrict__ keys,
                            const float* __restrict__ hard,
                            float* __restrict__ knT,   // [128][800]
                            float* __restrict__ hn) {  // [800][128]
    int m = blockIdx.x;      // 0..799
    int c = threadIdx.x;     // 0..127
    float kv = keys[m * 128 + c];
    float hv = hard[m * 128 + c];
    __shared__ float s1[128];
    __shared__ float s2[128];
    s1[c] = kv * kv;
    s2[c] = hv * hv;
    __syncthreads();
    for (int off = 64; off > 0; off >>= 1) {
        if (c < off) { s1[c] += s1[c + off]; s2[c] += s2[c + off]; }
        __syncthreads();
    }
    float ks = 1.0f / fmaxf(sqrtf(s1[0]), 1e-12f);
    float hs = 1.0f / fmaxf(sqrtf(s2[0]), 1e-12f);
    knT[c * 800 + m] = kv * ks;
    hn[m * 128 + c]  = hv * hs;
}

__global__ void prep_c0_k(const float* __restrict__ values, float* __restrict__ c0) {
    int c = threadIdx.x;  // 128 threads
    float s = 0.f;
    for (int m = 0; m < 10; ++m) s += values[m * 128 + c];
    c0[c] = s * 0.1f;
}

// ---------------- center conv1+pool: only pooled rect [45,83)^2, 16 co per block ----------------
__global__ void ce1_k(const float* __restrict__ x,   // (16,1,256,256)
                      const float* __restrict__ w,   // (32,1,3,3)
                      const float* __restrict__ bias,
                      float* __restrict__ out) {     // (16,32,128,128) rect only
    int bx = blockIdx.x;            // 16 b * 2 cog * 6 tiles
    int b = bx / 12, rem = bx % 12;
    int cog = rem / 6, tile = rem % 6;
    int idx = tile * 256 + threadIdx.x;
    if (idx >= 1444) return;
    int ph = 45 + idx / 38, pw = 45 + idx % 38;
    const float* xb = x + (size_t)b * 65536;
    float win[4][4];
#pragma unroll
    for (int r = 0; r < 4; ++r) {
        int ih = 2 * ph - 1 + r;
        bool vr = (ih >= 96 && ih < 160);
#pragma unroll
        for (int c = 0; c < 4; ++c) {
            int iw = 2 * pw - 1 + c;
            win[r][c] = (vr && iw >= 96 && iw < 160) ? xb[ih * 256 + iw] : 0.f;
        }
    }
#pragma unroll
    for (int co8 = 0; co8 < 16; ++co8) {
        int co = cog * 16 + co8;
        const float* w9 = w + co * 9;
        float bv = bias[co];
        float a00 = bv, a01 = bv, a10 = bv, a11 = bv;
#pragma unroll
        for (int kh = 0; kh < 3; ++kh)
#pragma unroll
            for (int kw = 0; kw < 3; ++kw) {
                float wv = w9[kh * 3 + kw];
                a00 += win[kh][kw] * wv;
                a01 += win[kh][kw + 1] * wv;
                a10 += win[kh + 1][kw] * wv;
                a11 += win[kh + 1][kw + 1] * wv;
            }
        float mx = fmaxf(fmaxf(a00, a01), fmaxf(a10, a11));
        out[((size_t)b * 32 + co) * 16384 + ph * 128 + pw] = fmaxf(mx, 0.f);
    }
}

// ---------------- skip conv1+pool: full, 16 co per thread ----------------
__global__ void se1_k(const float* __restrict__ x,   // (16,1,256,256)
                      const float* __restrict__ w,   // (16,1,3,3)
                      const float* __restrict__ bias,
                      float* __restrict__ out) {     // (16,16,128,128)
    int bx = blockIdx.x;            // 16 b * 64 tiles
    int b = bx >> 6, tile = bx & 63;
    int idx = tile * 256 + threadIdx.x;   // 0..16383
    int ph = idx >> 7, pw = idx & 127;
    const float* xb = x + (size_t)b * 65536;
    float win[4][4];
#pragma unroll
    for (int r = 0; r < 4; ++r) {
        int ih = 2 * ph - 1 + r;
        bool vr = (ih >= 0 && ih < 256);
#pragma unroll
        for (int c = 0; c < 4; ++c) {
            int iw = 2 * pw - 1 + c;
            win[r][c] = (vr && iw >= 0 && iw < 256) ? xb[ih * 256 + iw] : 0.f;
        }
    }
#pragma unroll
    for (int co = 0; co < 16; ++co) {
        const float* w9 = w + co * 9;
        float bv = bias[co];
        float a00 = bv, a01 = bv, a10 = bv, a11 = bv;
#pragma unroll
        for (int kh = 0; kh < 3; ++kh)
#pragma unroll
            for (int kw = 0; kw < 3; ++kw) {
                float wv = w9[kh * 3 + kw];
                a00 += win[kh][kw] * wv;
                a01 += win[kh][kw + 1] * wv;
                a10 += win[kh + 1][kw] * wv;
                a11 += win[kh + 1][kw + 1] * wv;
            }
        float mx = fmaxf(fmaxf(a00, a01), fmaxf(a10, a11));
        out[((size_t)b * 16 + co) * 16384 + idx] = fmaxf(mx, 0.f);
    }
}

// ---------------- center conv2 v3 (32->128) + relu + pool, region only, 8 co/thread ----------------
__global__ void __launch_bounds__(256) ce2_v3(
        const float* __restrict__ zc1,  // (16,32,128,128)
        const float* __restrict__ w,    // (128,32,3,3)
        const float* __restrict__ bias,
        float* __restrict__ zc) {       // (16,128,64,64) region only
    int bx = blockIdx.x;                // 16 b * 16 cog
    int b = bx >> 4, cog = bx & 15;
    const float* ib = zc1 + (size_t)b * 32 * 16384;
    for (int px = threadIdx.x; px < 324; px += 256) {
        int h = 23 + px / 18, ww = 23 + px % 18;
        float acc[8][4];
#pragma unroll
        for (int c8 = 0; c8 < 8; ++c8)
#pragma unroll
            for (int t = 0; t < 4; ++t) acc[c8][t] = 0.f;
        for (int ci = 0; ci < 32; ++ci) {
            const float* p = ib + ci * 16384 + (2 * h - 1) * 128 + (2 * ww - 1);
            float win[4][4];
#pragma unroll
            for (int r = 0; r < 4; ++r)
#pragma unroll
                for (int s = 0; s < 4; ++s) win[r][s] = p[r * 128 + s];
#pragma unroll
            for (int c8 = 0; c8 < 8; ++c8) {
                const float* w9 = w + ((size_t)(cog * 8 + c8) * 32 + ci) * 9;
#pragma unroll
                for (int kh = 0; kh < 3; ++kh)
#pragma unroll
                    for (int kw = 0; kw < 3; ++kw) {
                        float wv = w9[kh * 3 + kw];
                        acc[c8][0] += win[kh][kw] * wv;
                        acc[c8][1] += win[kh][kw + 1] * wv;
                        acc[c8][2] += win[kh + 1][kw] * wv;
                        acc[c8][3] += win[kh + 1][kw + 1] * wv;
                    }
            }
        }
#pragma unroll
        for (int c8 = 0; c8 < 8; ++c8) {
            int co = cog * 8 + c8;
            float mx = fmaxf(fmaxf(acc[c8][0], acc[c8][1]), fmaxf(acc[c8][2], acc[c8][3])) + bias[co];
            zc[((size_t)b * 128 + co) * 4096 + h * 64 + ww] = fmaxf(mx, 0.f);
        }
    }
}

// ---------------- skip conv2 (16->128) + relu + pool, 8 co per thread ----------------
__global__ void se2_v2(const float* __restrict__ zs1,  // (16,16,128,128)
                       const float* __restrict__ w,    // (128,16,3,3)
                       const float* __restrict__ bias,
                       float* __restrict__ zs) {       // (16,128,64,64)
    int bx = blockIdx.x;            // 16 b * 16 cog * 16 tiles = 4096
    int b = bx >> 8, rem = bx & 255;
    int cog = rem >> 4, tile = rem & 15;
    int px = tile * 256 + threadIdx.x;  // 0..4095
    int ph = px >> 6, pw = px & 63;
    const float* ib = zs1 + (size_t)b * 16 * 16384;
    float acc[8][4];
#pragma unroll
    for (int c8 = 0; c8 < 8; ++c8)
#pragma unroll
        for (int t = 0; t < 4; ++t) acc[c8][t] = 0.f;
    for (int ci = 0; ci < 16; ++ci) {
        const float* p = ib + ci * 16384;
        float win[4][4];
#pragma unroll
        for (int r = 0; r < 4; ++r) {
            int rr = 2 * ph - 1 + r;
            bool vr = (rr >= 0 && rr < 128);
#pragma unroll
            for (int s = 0; s < 4; ++s) {
                int cc = 2 * pw - 1 + s;
                win[r][s] = (vr && cc >= 0 && cc < 128) ? p[rr * 128 + cc] : 0.f;
            }
        }
#pragma unroll
        for (int c8 = 0; c8 < 8; ++c8) {
            const float* w9 = w + ((size_t)(cog * 8 + c8) * 16 + ci) * 9;
#pragma unroll
            for (int kh = 0; kh < 3; ++kh)
#pragma unroll
                for (int kw = 0; kw < 3; ++kw) {
                    float wv = w9[kh * 3 + kw];
                    acc[c8][0] += win[kh][kw] * wv;
                    acc[c8][1] += win[kh][kw + 1] * wv;
                    acc[c8][2] += win[kh + 1][kw] * wv;
                    acc[c8][3] += win[kh + 1][kw + 1] * wv;
                }
        }
    }
#pragma unroll
    for (int c8 = 0; c8 < 8; ++c8) {
        int co = cog * 8 + c8;
        float bv = bias[co];
        float mx = fmaxf(fmaxf(acc[c8][0], acc[c8][1]), fmaxf(acc[c8][2], acc[c8][3])) + bv;
        zs[((size_t)b * 128 + co) * 4096 + px] = fmaxf(mx, 0.f);
    }
}

// ---------------- center matching: one wave per in-region query ----------------
__global__ void __launch_bounds__(64) match_center_k(
        const float* __restrict__ zc,     // (16,128,64,64)
        const float* __restrict__ knT,    // [128][800] normalized
        const float* __restrict__ values, // (800,128)
        float* __restrict__ dcat) {       // (16,256,64,64), ch 0..127
    int bq = blockIdx.x;
    int b = bq / 324, q = bq % 324;
    int h = 23 + q / 18, ww = 23 + q % 18;
    int p = h * 64 + ww;
    int lane = threadIdx.x;
    __shared__ float qs[128];
    const float* zb = zc + ((size_t)b * 128) * 4096 + p;
    float v0 = zb[(size_t)lane * 4096];
    float v1 = zb[(size_t)(lane + 64) * 4096];
    float ss = v0 * v0 + v1 * v1;
#pragma unroll
    for (int off = 32; off > 0; off >>= 1) ss += __shfl_xor(ss, off);
    float sc = 1.0f / fmaxf(sqrtf(ss), 1e-12f);
    qs[lane] = v0 * sc;
    qs[lane + 64] = v1 * sc;
    __syncthreads();

    float sim[13];
#pragma unroll
    for (int k = 0; k < 13; ++k) sim[k] = 0.f;
    for (int c = 0; c < 128; ++c) {
        float qc = qs[c];
        const float* kr = knT + c * 800 + lane;
#pragma unroll
        for (int k = 0; k < 13; ++k) {
            int m = lane + (k << 6);
            if (m < 800) sim[k] += qc * kr[k << 6];
        }
    }
#pragma unroll
    for (int k = 0; k < 13; ++k)
        if (lane + (k << 6) >= 800) sim[k] = NEG_INF;

    float topv[11]; int topm[11];
#pragma unroll
    for (int t = 0; t < 11; ++t) {
        float bvv = NEG_INF; int bm = 0x7fffffff;
#pragma unroll
        for (int k = 0; k < 13; ++k) {
            if (sim[k] > bvv) { bvv = sim[k]; bm = lane + (k << 6); }
        }
#pragma unroll
        for (int off = 32; off > 0; off >>= 1) {
            float ov = __shfl_xor(bvv, off);
            int om = __shfl_xor(bm, off);
            if (ov > bvv || (ov == bvv && om < bm)) { bvv = ov; bm = om; }
        }
        topv[t] = bvv; topm[t] = bm;
        if ((bm & 63) == lane) {
            int kk = bm >> 6;
#pragma unroll
            for (int k = 0; k < 13; ++k)
                if (k == kk) sim[k] = NEG_INF;
        }
    }
    if (topv[9] - topv[10] < 1e-4f) {
        double s9 = 0.0, s10 = 0.0;
        for (int c = 0; c < 128; ++c) {
            double qc = (double)qs[c];
            s9  += qc * (double)knT[c * 800 + topm[9]];
            s10 += qc * (double)knT[c * 800 + topm[10]];
        }
        if ((s10 > s9) || (s10 == s9 && topm[10] < topm[9])) {
            topv[9] = topv[10]; topm[9] = topm[10];
        }
    }
    float mx = topv[0];
    float e[10], ssum = 0.f;
#pragma unroll
    for (int t = 0; t < 10; ++t) { e[t] = expf(topv[t] - mx); ssum += e[t]; }
    float inv = 1.0f / ssum;
    float o0 = 0.f, o1 = 0.f;
#pragma unroll
    for (int t = 0; t < 10; ++t) {
        float wt = e[t] * inv;
        const float* vr = values + (size_t)topm[t] * 128;
        o0 += wt * vr[lane];
        o1 += wt * vr[lane + 64];
    }
    float* ob = dcat + ((size_t)b * 256) * 4096 + p;
    ob[(size_t)lane * 4096] = o0;
    ob[(size_t)(lane + 64) * 4096] = o1;
}

// ---------------- constant fill for out-of-region center matches ----------------
__global__ void fill_c0_k(const float* __restrict__ c0, float* __restrict__ dcat) {
    int idx = blockIdx.x * 256 + threadIdx.x;
    int p = idx & 4095;
    int c = (idx >> 12) & 127;
    int b = idx >> 19;
    int h = p >> 6, ww = p & 63;
    if (h >= 23 && h <= 40 && ww >= 23 && ww <= 40) return;
    dcat[((size_t)b * 256 + c) * 4096 + p] = c0[c];
}

// ---------------- skip matching v3: block = 64 queries, 32-row key chunks, 50.2 KB LDS ----------------
__global__ void __launch_bounds__(256) match_skip_v3(
        const float* __restrict__ zs,    // (16,128,64,64)
        const float* __restrict__ hn,    // (800,128) normalized
        const float* __restrict__ hard,  // (800,128) raw
        float* __restrict__ dcat) {      // ch 128..255
    __shared__ float sh[12800];          // 51.2 KB: shq[64*132] | max(shh[32*132], red[64*17*4])
    float* shq = sh;
    float* shh = sh + 8448;
    int b = blockIdx.x >> 6, pt = blockIdx.x & 63;
    int pbase = pt * 64;
    int tid = threadIdx.x;

    for (int f = tid; f < 8192; f += 256) {
        int c = f >> 6, p = f & 63;
        shq[p * 132 + c] = zs[((size_t)b * 128 + c) * 4096 + pbase + p];
    }

    int qs = tid >> 4, ms = tid & 15;
    float v1[4], v2[4]; int i1[4], i2[4];
#pragma unroll
    for (int u = 0; u < 4; ++u) { v1[u] = NEG_INF; v2[u] = NEG_INF; i1[u] = 0x7fffffff; i2[u] = 0x7fffffff; }

    for (int chunk = 0; chunk < 25; ++chunk) {
        int mbase = chunk * 32;
        __syncthreads();
        for (int f = tid; f < 4096; f += 256) {
            int row = f >> 7, c = f & 127;
            shh[row * 132 + c] = hn[(size_t)(mbase + row) * 128 + c];
        }
        __syncthreads();
        float s[4][2];
#pragma unroll
        for (int u = 0; u < 4; ++u)
#pragma unroll
            for (int j = 0; j < 2; ++j) s[u][j] = 0.f;
        for (int c4 = 0; c4 < 32; ++c4) {
            float4 qv[4], hv[2];
#pragma unroll
            for (int u = 0; u < 4; ++u)
                qv[u] = *(const float4*)(shq + (qs * 4 + u) * 132 + c4 * 4);
#pragma unroll
            for (int j = 0; j < 2; ++j)
                hv[j] = *(const float4*)(shh + (ms + 16 * j) * 132 + c4 * 4);
#pragma unroll
            for (int u = 0; u < 4; ++u)
#pragma unroll
                for (int j = 0; j < 2; ++j)
                    s[u][j] += qv[u].x * hv[j].x + qv[u].y * hv[j].y +
                               qv[u].z * hv[j].z + qv[u].w * hv[j].w;
        }
#pragma unroll
        for (int u = 0; u < 4; ++u)
#pragma unroll
            for (int j = 0; j < 2; ++j) {
                int m = mbase + ms + 16 * j;
                float sv = s[u][j];
                if (sv > v1[u] || (sv == v1[u] && m < i1[u])) {
                    v2[u] = v1[u]; i2[u] = i1[u]; v1[u] = sv; i1[u] = m;
                } else if (sv > v2[u] || (sv == v2[u] && m < i2[u])) {
                    v2[u] = sv; i2[u] = m;
                }
            }
    }
    __syncthreads();
    float4* red = (float4*)(sh + 8448);  // [64 q][17 slots] = 4352 floats
#pragma unroll
    for (int u = 0; u < 4; ++u)
        red[(qs * 4 + u) * 17 + ms] =
            make_float4(v1[u], v2[u], __int_as_float(i1[u]), __int_as_float(i2[u]));
    __syncthreads();
    if (tid < 64) {
        int q = tid;
        float V1 = NEG_INF, V2 = NEG_INF; int I1 = 0x7fffffff, I2 = 0x7fffffff;
        for (int k = 0; k < 16; ++k) {
            float4 e = red[q * 17 + k];
            float cv[2] = { e.x, e.y };
            int ci_[2] = { __float_as_int(e.z), __float_as_int(e.w) };
#pragma unroll
            for (int t = 0; t < 2; ++t) {
                float v = cv[t]; int i = ci_[t];
                if (v > V1 || (v == V1 && i < I1)) { V2 = V1; I2 = I1; V1 = v; I1 = i; }
                else if (v > V2 || (v == V2 && i < I2)) { V2 = v; I2 = i; }
            }
        }
        float qn2 = 0.f;
        for (int c = 0; c < 128; ++c) { float qc = shq[q * 132 + c]; qn2 += qc * qc; }
        float tau = 1e-4f * sqrtf(qn2) + 1e-12f;
        int bi = I1;
        if (V1 - V2 < tau && I2 != 0x7fffffff) {
            double d1 = 0.0, d2 = 0.0;
            const float* h1 = hn + (size_t)I1 * 128;
            const float* h2 = hn + (size_t)I2 * 128;
            for (int c = 0; c < 128; ++c) {
                double qc = (double)shq[q * 132 + c];
                d1 += qc * (double)h1[c];
                d2 += qc * (double)h2[c];
            }
            if ((d2 > d1) || (d2 == d1 && I2 < I1)) bi = I2;
        }
        const float* hr = hard + (size_t)bi * 128;
        float* ob = dcat + ((size_t)b * 256 + 128) * 4096 + pbase + q;
        for (int c = 0; c < 128; ++c) ob[(size_t)c * 4096] = hr[c];
    }
}

// ---------------- decoder conv1 v4: weight-staged LDS, 4 px/thread, K-split 2 ----------------
// grid: 16b * 4cog * 4tiles * 2ksplit = 512 blocks, 256 thr. Writes fp32 partials (no bias/relu).
__global__ void __launch_bounds__(256, 2) dec1_v4(
        const float* __restrict__ dcat, // (16,256,64,64)
        const float* __restrict__ w,    // (64,256,3,3)
        float* __restrict__ pA,         // (16,64,64,64) partial ksplit 0
        float* __restrict__ pB) {       // (16,64,64,64) partial ksplit 1
    __shared__ float xs[2][4760];       // 4 ci x 34x35 halo tile
    __shared__ float wsh[2][768];       // 4 ci x 16 co x 12 (9 used, pad for float4)
    int bx = blockIdx.x;
    int b = bx >> 5, rem = bx & 31;
    int cog = rem >> 3, tile = (rem >> 1) & 3, ks = rem & 1;
    int ph0 = (tile >> 1) * 32, pw0 = (tile & 1) * 32;
    int tid = threadIdx.x;
    int pr = tid >> 4, pc = tid & 15;

    const float* ib = dcat + ((size_t)b * 256 + (size_t)ks * 128) * 4096;
    const float* wb = w + (size_t)(cog * 16) * 2304 + (size_t)ks * 128 * 9;

    // chunk-invariant staging descriptors
    int xg[19];
#pragma unroll
    for (int k = 0; k < 19; ++k) {
        int f = tid + k * 256;
        xg[k] = -1;
        if (f < 4760) {
            int ci_l = f / 1190, pos = f % 1190;
            int r = pos / 35, c = pos % 35;
            int row = ph0 - 1 + r, col = pw0 - 1 + c;
            if (c < 34 && row >= 0 && row < 64 && col >= 0 && col < 64)
                xg[k] = ci_l * 4096 + row * 64 + col;
        }
    }
    int wg[3], wl[3];
#pragma unroll
    for (int k = 0; k < 3; ++k) {
        int t = tid + k * 256;
        wg[k] = -1; wl[k] = 0;
        if (t < 576) {
            int ci_l = t / 144, r2 = t % 144;
            int co = r2 / 9, j = r2 % 9;
            wg[k] = co * 2304 + ci_l * 9 + j;
            wl[k] = ci_l * 192 + co * 12 + j;
        }
    }

    // stage chunk 0
#pragma unroll
    for (int k = 0; k < 19; ++k) {
        int f = tid + k * 256;
        if (f < 4760) xs[0][f] = (xg[k] >= 0) ? ib[xg[k]] : 0.f;
    }
#pragma unroll
    for (int k = 0; k < 3; ++k)
        if (wg[k] >= 0) wsh[0][wl[k]] = wb[wg[k]];
    __syncthreads();

    float acc[16][4];
#pragma unroll
    for (int co = 0; co < 16; ++co)
#pragma unroll
        for (int q = 0; q < 4; ++q) acc[co][q] = 0.f;

    for (int chunk = 0; chunk < 32; ++chunk) {
        int cur = chunk & 1;
        float pfx[19], pfw[3];
        if (chunk < 31) {
            const float* ibn = ib + (size_t)(chunk + 1) * 4 * 4096;
            const float* wbn = wb + (chunk + 1) * 36;
#pragma unroll
            for (int k = 0; k < 19; ++k) {
                int f = tid + k * 256;
                if (f < 4760) pfx[k] = (xg[k] >= 0) ? ibn[xg[k]] : 0.f;
            }
#pragma unroll
            for (int k = 0; k < 3; ++k)
                if (wg[k] >= 0) pfw[k] = wbn[wg[k]];
        }
#pragma unroll 2
        for (int ci_l = 0; ci_l < 4; ++ci_l) {
            const float* xp = &xs[cur][ci_l * 1190 + (2 * pr) * 35 + 2 * pc];
            float xw[4][4];
#pragma unroll
            for (int r = 0; r < 4; ++r)
#pragma unroll
                for (int c = 0; c < 4; ++c) xw[r][c] = xp[r * 35 + c];
            const float* wp = &wsh[cur][ci_l * 192];
#pragma unroll
            for (int co = 0; co < 16; ++co) {
                float4 w0 = *(const float4*)(wp + co * 12);
                float4 w1 = *(const float4*)(wp + co * 12 + 4);
                float4 w2 = *(const float4*)(wp + co * 12 + 8);
                float wv[9] = { w0.x, w0.y, w0.z, w0.w, w1.x, w1.y, w1.z, w1.w, w2.x };
#pragma unroll
                for (int q = 0; q < 4; ++q) {
                    int qr = q >> 1, qc = q & 1;
                    float s = acc[co][q];
#pragma unroll
                    for (int kh = 0; kh < 3; ++kh)
#pragma unroll
                        for (int kw = 0; kw < 3; ++kw)
                            s += xw[qr + kh][qc + kw] * wv[kh * 3 + kw];
                    acc[co][q] = s;
                }
            }
        }
        if (chunk < 31) {
#pragma unroll
            for (int k = 0; k < 19; ++k) {
                int f = tid + k * 256;
                if (f < 4760) xs[1 - cur][f] = pfx[k];
            }
#pragma unroll
            for (int k = 0; k < 3; ++k)
                if (wg[k] >= 0) wsh[1 - cur][wl[k]] = pfw[k];
            __syncthreads();
        }
    }
    float* ob = ((ks == 0) ? pA : pB) + ((size_t)b * 64 + cog * 16) * 4096;
#pragma unroll
    for (int co = 0; co < 16; ++co)
#pragma unroll
        for (int q = 0; q < 4; ++q) {
            int row = ph0 + 2 * pr + (q >> 1), col = pw0 + 2 * pc + (q & 1);
            ob[(size_t)co * 4096 + row * 64 + col] = acc[co][q];
        }
}

// ---------------- dec1 partial reduce: d1 = relu(pA + pB + bias), in-place over pA ----------------
__global__ void dec1_add_k(float* __restrict__ pA, const float* __restrict__ pB,
                           const float* __restrict__ bias) {
    int idx = blockIdx.x * 256 + threadIdx.x;  // 16*64*4096 = 4194304
    int c = (idx >> 12) & 63;
    float v = pA[idx] + pB[idx] + bias[c];
    pA[idx] = fmaxf(v, 0.f);
}

// ---------------- transposed conv v2: quad-parity, 16 co per thread ----------------
template <int CIN, int COUT, int COG, int H>
__global__ void __launch_bounds__(256) tconv_v2(
        const float* __restrict__ x,   // (16,CIN,H,H)
        const float* __restrict__ w,   // (CIN,COUT,4,4)
        const float* __restrict__ bias,
        float* __restrict__ out) {     // (16,COUT,2H,2H)
    constexpr int NCOG = COUT / COG;
    constexpr int TPS = H / 16;           // quad tiles per side
    constexpr int TILES = TPS * TPS;
    constexpr int HO = 2 * H;
    int bx = blockIdx.x;                  // 16 * NCOG * TILES
    int b = bx / (NCOG * TILES), rem = bx % (NCOG * TILES);
    int cog = rem / TILES, tile = rem % TILES;
    int ti = tile / TPS, tj = tile % TPS;
    int tid = threadIdx.x;
    int i = ti * 16 + (tid >> 4);
    int j = tj * 16 + (tid & 15);

    float acc[2][2][COG];
#pragma unroll
    for (int pr = 0; pr < 2; ++pr)
#pragma unroll
        for (int pc = 0; pc < 2; ++pc)
#pragma unroll
            for (int co = 0; co < COG; ++co) acc[pr][pc][co] = 0.f;

    const float* xb = x + (size_t)b * CIN * H * H;
    for (int ci = 0; ci < CIN; ++ci) {
        const float* xp = xb + (size_t)ci * H * H;
        float xr[3][3];
#pragma unroll
        for (int dr = 0; dr < 3; ++dr) {
            int gr = i - 1 + dr;
            bool vr = (gr >= 0 && gr < H);
#pragma unroll
            for (int dc = 0; dc < 3; ++dc) {
                int gc = j - 1 + dc;
                xr[dr][dc] = (vr && gc >= 0 && gc < H) ? xp[gr * H + gc] : 0.f;
            }
        }
#pragma unroll
        for (int co = 0; co < COG; ++co) {
            const float* wp = w + (((size_t)ci * COUT + cog * COG + co) << 4);
            float wr[16];
#pragma unroll
            for (int k = 0; k < 16; ++k) wr[k] = wp[k];
#pragma unroll
            for (int pr = 0; pr < 2; ++pr)
#pragma unroll
                for (int a = 0; a < 2; ++a)
#pragma unroll
                    for (int pc = 0; pc < 2; ++pc)
#pragma unroll
                        for (int bb = 0; bb < 2; ++bb)
                            acc[pr][pc][co] += xr[pr + a][pc + bb] *
                                               wr[(3 - pr - 2 * a) * 4 + (3 - pc - 2 * bb)];
        }
    }
#pragma unroll
    for (int co = 0; co < COG; ++co) {
        float bv = bias[cog * COG + co];
        float* ob = out + ((size_t)b * COUT + cog * COG + co) * HO * HO;
#pragma unroll
        for (int pr = 0; pr < 2; ++pr)
#pragma unroll
            for (int pc = 0; pc < 2; ++pc)
                ob[(2 * i + pr) * HO + 2 * j + pc] = fmaxf(acc[pr][pc][co] + bv, 0.f);
    }
}

// ---------------- final conv (16->1) 3x3, 4 px per thread ----------------
__global__ void final_v2(const float* __restrict__ t2,  // (16,16,256,256)
                         const float* __restrict__ w,   // (1,16,3,3)
                         const float* __restrict__ bias,
                         float* __restrict__ out) {     // (16,1,256,256)
    int g = blockIdx.x * 256 + threadIdx.x;   // 262144 threads
    int pxb = g * 4;
    int b = pxb >> 16, p = pxb & 65535;
    int h = p >> 8, c0 = p & 255;
    const float* tb = t2 + (size_t)b * 16 * 65536;
    float acc[4];
    float bv = bias[0];
#pragma unroll
    for (int t = 0; t < 4; ++t) acc[t] = bv;
    for (int ci = 0; ci < 16; ++ci) {
        const float* pp = tb + (size_t)ci * 65536;
        const float* w9 = w + ci * 9;
        float win[3][6];
#pragma unroll
        for (int dr = 0; dr < 3; ++dr) {
            int rr = h - 1 + dr;
            bool vr = (rr >= 0 && rr < 256);
#pragma unroll
            for (int dc = 0; dc < 6; ++dc) {
                int cc = c0 - 1 + dc;
                win[dr][dc] = (vr && cc >= 0 && cc < 256) ? pp[rr * 256 + cc] : 0.f;
            }
        }
#pragma unroll
        for (int t = 0; t < 4; ++t)
#pragma unroll
            for (int dr = 0; dr < 3; ++dr)
#pragma unroll
                for (int dc = 0; dc < 3; ++dc)
                    acc[t] += win[dr][t + dc] * w9[dr * 3 + dc];
    }
    *(float4*)(out + pxb) = make_float4(acc[0], acc[1], acc[2], acc[3]);
}

// ---------------- launch ----------------
extern "C" void kernel_launch(void* const* d_in, const int* in_sizes, int n_in,
                              void* d_out, int out_size, void* d_ws, size_t ws_size,
                              hipStream_t stream) {
    (void)in_sizes; (void)n_in; (void)out_size; (void)ws_size;
    const float* x     = (const float*)d_in[0];
    const float* cw1   = (const float*)d_in[1];
    const float* cb1   = (const float*)d_in[2];
    const float* cw2   = (const float*)d_in[3];
    const float* cb2   = (const float*)d_in[4];
    const float* sw1   = (const float*)d_in[5];
    const float* sb1   = (const float*)d_in[6];
    const float* sw2   = (const float*)d_in[7];
    const float* sb2   = (const float*)d_in[8];
    const float* mkeys = (const float*)d_in[9];
    const float* mvals = (const float*)d_in[10];
    const float* mhard = (const float*)d_in[11];
    const float* dw1   = (const float*)d_in[12];
    const float* db1   = (const float*)d_in[13];
    const float* tw1   = (const float*)d_in[14];
    const float* tb1   = (const float*)d_in[15];
    const float* tw2   = (const float*)d_in[16];
    const float* tb2   = (const float*)d_in[17];
    const float* dw2   = (const float*)d_in[18];
    const float* db2   = (const float*)d_in[19];
    float* out = (float*)d_out;
    float* ws  = (float*)d_ws;

    const size_t OFF_KN  = 0;                   // knT: 128*800
    const size_t OFF_HN  = 102400;              // hn:  800*128
    const size_t OFF_C0  = 204800;              // c0:  128
    const size_t OFF_R14 = 204928;              // zc1 -> zs -> t1
    const size_t OFF_R2  = OFF_R14 + 8388608;   // zc -> dec1 partial B
    const size_t OFF_R3  = OFF_R2 + 8388608;    // zs1 -> dec1 partial A / d1
    const size_t OFF_R5  = OFF_R3 + 4194304;    // dcat -> t2

    float* knT  = ws + OFF_KN;
    float* hn   = ws + OFF_HN;
    float* c0   = ws + OFF_C0;
    float* zc1  = ws + OFF_R14;
    float* zs   = ws + OFF_R14;
    float* t1   = ws + OFF_R14;
    float* zc   = ws + OFF_R2;
    float* pB   = ws + OFF_R2;
    float* zs1  = ws + OFF_R3;
    float* d1b  = ws + OFF_R3;
    float* dcat = ws + OFF_R5;
    float* t2   = ws + OFF_R5;

    prep_norm_k<<<800, 128, 0, stream>>>(mkeys, mhard, knT, hn);
    prep_c0_k<<<1, 128, 0, stream>>>(mvals, c0);

    ce1_k<<<16 * 2 * 6, 256, 0, stream>>>(x, cw1, cb1, zc1);
    se1_k<<<16 * 64, 256, 0, stream>>>(x, sw1, sb1, zs1);
    ce2_v3<<<16 * 16, 256, 0, stream>>>(zc1, cw2, cb2, zc);
    se2_v2<<<16 * 16 * 16, 256, 0, stream>>>(zs1, sw2, sb2, zs);  // overwrites zc1 (dead)

    match_center_k<<<16 * 324, 64, 0, stream>>>(zc, knT, mvals, dcat);
    fill_c0_k<<<32768, 256, 0, stream>>>(c0, dcat);
    match_skip_v3<<<16 * 64, 256, 0, stream>>>(zs, hn, mhard, dcat);

    // dec1: K-split partials into pA (=d1b, zs1 dead) and pB (=zc, dead after match_center)
    dec1_v4<<<512, 256, 0, stream>>>(dcat, dw1, d1b, pB);
    dec1_add_k<<<16384, 256, 0, stream>>>(d1b, pB, db1);

    tconv_v2<64, 32, 16, 64><<<16 * 2 * 16, 256, 0, stream>>>(d1b, tw1, tb1, t1);   // overwrites zs (dead)
    tconv_v2<32, 16, 16, 128><<<16 * 1 * 64, 256, 0, stream>>>(t1, tw2, tb2, t2);   // overwrites dcat (dead)
    final_v2<<<1024, 256, 0, stream>>>(t2, dw2, db2, out);  // 4 px/thread, 1M px total
}

// Round 6
// 1328.607 us; speedup vs baseline: 6.3898x; 1.2129x over previous
//
#include <hip/hip_runtime.h>
#include <cstdint>
#include <cstddef>

#define NEG_INF (-3.0e38f)

// ---------------- prep: normalize keys (row-major) + hard (row-major) ----------------
__global__ void prep_norm_k(const float* __restrict__ keys,
                            const float* __restrict__ hard,
                            float* __restrict__ knR,   // [800][128] normalized keys
                            float* __restrict__ hn) {  // [800][128] normalized hard
    int m = blockIdx.x;      // 0..799
    int c = threadIdx.x;     // 0..127
    float kv = keys[m * 128 + c];
    float hv = hard[m * 128 + c];
    __shared__ float s1[128];
    __shared__ float s2[128];
    s1[c] = kv * kv;
    s2[c] = hv * hv;
    __syncthreads();
    for (int off = 64; off > 0; off >>= 1) {
        if (c < off) { s1[c] += s1[c + off]; s2[c] += s2[c + off]; }
        __syncthreads();
    }
    float ks = 1.0f / fmaxf(sqrtf(s1[0]), 1e-12f);
    float hs = 1.0f / fmaxf(sqrtf(s2[0]), 1e-12f);
    knR[m * 128 + c] = kv * ks;
    hn[m * 128 + c]  = hv * hs;
}

__global__ void prep_c0_k(const float* __restrict__ values, float* __restrict__ c0) {
    int c = threadIdx.x;  // 128 threads
    float s = 0.f;
    for (int m = 0; m < 10; ++m) s += values[m * 128 + c];
    c0[c] = s * 0.1f;
}

// ---------------- center conv1+pool: only pooled rect [45,83)^2, 16 co per block ----------------
__global__ void ce1_k(const float* __restrict__ x,   // (16,1,256,256)
                      const float* __restrict__ w,   // (32,1,3,3)
                      const float* __restrict__ bias,
                      float* __restrict__ out) {     // (16,32,128,128) rect only
    int bx = blockIdx.x;            // 16 b * 2 cog * 6 tiles
    int b = bx / 12, rem = bx % 12;
    int cog = rem / 6, tile = rem % 6;
    int idx = tile * 256 + threadIdx.x;
    if (idx >= 1444) return;
    int ph = 45 + idx / 38, pw = 45 + idx % 38;
    const float* xb = x + (size_t)b * 65536;
    float win[4][4];
#pragma unroll
    for (int r = 0; r < 4; ++r) {
        int ih = 2 * ph - 1 + r;
        bool vr = (ih >= 96 && ih < 160);
#pragma unroll
        for (int c = 0; c < 4; ++c) {
            int iw = 2 * pw - 1 + c;
            win[r][c] = (vr && iw >= 96 && iw < 160) ? xb[ih * 256 + iw] : 0.f;
        }
    }
#pragma unroll
    for (int co8 = 0; co8 < 16; ++co8) {
        int co = cog * 16 + co8;
        const float* w9 = w + co * 9;
        float bv = bias[co];
        float a00 = bv, a01 = bv, a10 = bv, a11 = bv;
#pragma unroll
        for (int kh = 0; kh < 3; ++kh)
#pragma unroll
            for (int kw = 0; kw < 3; ++kw) {
                float wv = w9[kh * 3 + kw];
                a00 += win[kh][kw] * wv;
                a01 += win[kh][kw + 1] * wv;
                a10 += win[kh + 1][kw] * wv;
                a11 += win[kh + 1][kw + 1] * wv;
            }
        float mx = fmaxf(fmaxf(a00, a01), fmaxf(a10, a11));
        out[((size_t)b * 32 + co) * 16384 + ph * 128 + pw] = fmaxf(mx, 0.f);
    }
}

// ---------------- skip conv1+pool: full, 16 co per thread ----------------
__global__ void se1_k(const float* __restrict__ x,   // (16,1,256,256)
                      const float* __restrict__ w,   // (16,1,3,3)
                      const float* __restrict__ bias,
                      float* __restrict__ out) {     // (16,16,128,128)
    int bx = blockIdx.x;            // 16 b * 64 tiles
    int b = bx >> 6, tile = bx & 63;
    int idx = tile * 256 + threadIdx.x;   // 0..16383
    int ph = idx >> 7, pw = idx & 127;
    const float* xb = x + (size_t)b * 65536;
    float win[4][4];
#pragma unroll
    for (int r = 0; r < 4; ++r) {
        int ih = 2 * ph - 1 + r;
        bool vr = (ih >= 0 && ih < 256);
#pragma unroll
        for (int c = 0; c < 4; ++c) {
            int iw = 2 * pw - 1 + c;
            win[r][c] = (vr && iw >= 0 && iw < 256) ? xb[ih * 256 + iw] : 0.f;
        }
    }
#pragma unroll
    for (int co = 0; co < 16; ++co) {
        const float* w9 = w + co * 9;
        float bv = bias[co];
        float a00 = bv, a01 = bv, a10 = bv, a11 = bv;
#pragma unroll
        for (int kh = 0; kh < 3; ++kh)
#pragma unroll
            for (int kw = 0; kw < 3; ++kw) {
                float wv = w9[kh * 3 + kw];
                a00 += win[kh][kw] * wv;
                a01 += win[kh][kw + 1] * wv;
                a10 += win[kh + 1][kw] * wv;
                a11 += win[kh + 1][kw + 1] * wv;
            }
        float mx = fmaxf(fmaxf(a00, a01), fmaxf(a10, a11));
        out[((size_t)b * 16 + co) * 16384 + idx] = fmaxf(mx, 0.f);
    }
}

// ---------------- center conv2 v3 (32->128) + relu + pool -> query-major zcq ----------------
__global__ void __launch_bounds__(256) ce2_v3(
        const float* __restrict__ zc1,  // (16,32,128,128)
        const float* __restrict__ w,    // (128,32,3,3)
        const float* __restrict__ bias,
        float* __restrict__ zcq) {      // (16*324, 128) query-major
    int bx = blockIdx.x;                // 16 b * 16 cog
    int b = bx >> 4, cog = bx & 15;
    const float* ib = zc1 + (size_t)b * 32 * 16384;
    for (int px = threadIdx.x; px < 324; px += 256) {
        int h = 23 + px / 18, ww = 23 + px % 18;
        float acc[8][4];
#pragma unroll
        for (int c8 = 0; c8 < 8; ++c8)
#pragma unroll
            for (int t = 0; t < 4; ++t) acc[c8][t] = 0.f;
        for (int ci = 0; ci < 32; ++ci) {
            const float* p = ib + ci * 16384 + (2 * h - 1) * 128 + (2 * ww - 1);
            float win[4][4];
#pragma unroll
            for (int r = 0; r < 4; ++r)
#pragma unroll
                for (int s = 0; s < 4; ++s) win[r][s] = p[r * 128 + s];
#pragma unroll
            for (int c8 = 0; c8 < 8; ++c8) {
                const float* w9 = w + ((size_t)(cog * 8 + c8) * 32 + ci) * 9;
#pragma unroll
                for (int kh = 0; kh < 3; ++kh)
#pragma unroll
                    for (int kw = 0; kw < 3; ++kw) {
                        float wv = w9[kh * 3 + kw];
                        acc[c8][0] += win[kh][kw] * wv;
                        acc[c8][1] += win[kh][kw + 1] * wv;
                        acc[c8][2] += win[kh + 1][kw] * wv;
                        acc[c8][3] += win[kh + 1][kw + 1] * wv;
                    }
            }
        }
#pragma unroll
        for (int c8 = 0; c8 < 8; ++c8) {
            int co = cog * 8 + c8;
            float mx = fmaxf(fmaxf(acc[c8][0], acc[c8][1]), fmaxf(acc[c8][2], acc[c8][3])) + bias[co];
            zcq[((size_t)(b * 324 + px)) * 128 + co] = fmaxf(mx, 0.f);
        }
    }
}

// ---------------- skip conv2 (16->128) + relu + pool, 8 co per thread ----------------
__global__ void se2_v2(const float* __restrict__ zs1,  // (16,16,128,128)
                       const float* __restrict__ w,    // (128,16,3,3)
                       const float* __restrict__ bias,
                       float* __restrict__ zs) {       // (16,128,64,64)
    int bx = blockIdx.x;            // 16 b * 16 cog * 16 tiles = 4096
    int b = bx >> 8, rem = bx & 255;
    int cog = rem >> 4, tile = rem & 15;
    int px = tile * 256 + threadIdx.x;  // 0..4095
    int ph = px >> 6, pw = px & 63;
    const float* ib = zs1 + (size_t)b * 16 * 16384;
    float acc[8][4];
#pragma unroll
    for (int c8 = 0; c8 < 8; ++c8)
#pragma unroll
        for (int t = 0; t < 4; ++t) acc[c8][t] = 0.f;
    for (int ci = 0; ci < 16; ++ci) {
        const float* p = ib + ci * 16384;
        float win[4][4];
#pragma unroll
        for (int r = 0; r < 4; ++r) {
            int rr = 2 * ph - 1 + r;
            bool vr = (rr >= 0 && rr < 128);
#pragma unroll
            for (int s = 0; s < 4; ++s) {
                int cc = 2 * pw - 1 + s;
                win[r][s] = (vr && cc >= 0 && cc < 128) ? p[rr * 128 + cc] : 0.f;
            }
        }
#pragma unroll
        for (int c8 = 0; c8 < 8; ++c8) {
            const float* w9 = w + ((size_t)(cog * 8 + c8) * 16 + ci) * 9;
#pragma unroll
            for (int kh = 0; kh < 3; ++kh)
#pragma unroll
                for (int kw = 0; kw < 3; ++kw) {
                    float wv = w9[kh * 3 + kw];
                    acc[c8][0] += win[kh][kw] * wv;
                    acc[c8][1] += win[kh][kw + 1] * wv;
                    acc[c8][2] += win[kh + 1][kw] * wv;
                    acc[c8][3] += win[kh + 1][kw + 1] * wv;
                }
        }
    }
#pragma unroll
    for (int c8 = 0; c8 < 8; ++c8) {
        int co = cog * 8 + c8;
        float bv = bias[co];
        float mx = fmaxf(fmaxf(acc[c8][0], acc[c8][1]), fmaxf(acc[c8][2], acc[c8][3])) + bv;
        zs[((size_t)b * 128 + co) * 4096 + px] = fmaxf(mx, 0.f);
    }
}

// ---------------- center matching v2: LDS-staged keys, 2 queries/wave, 8/block ----------------
__global__ void __launch_bounds__(256) match_center_v2(
        const float* __restrict__ zcq,    // (16*324, 128) raw queries
        const float* __restrict__ knR,    // (800,128) normalized keys
        const float* __restrict__ values, // (800,128)
        float* __restrict__ dcat) {       // (16,256,64,64), ch 0..127
    __shared__ float shk[128 * 65];       // key chunk transposed [c][kk], pad 65
    __shared__ float qint[4 * 256];       // per wave: [c][2] normalized queries
    int tid = threadIdx.x;
    int w = tid >> 6, lane = tid & 63;
    int g0 = blockIdx.x * 8 + 2 * w;      // global query index of this wave's pair

    // load + normalize this wave's 2 queries (coalesced from zcq)
#pragma unroll
    for (int i = 0; i < 2; ++i) {
        const float* qp = zcq + (size_t)(g0 + i) * 128;
        float v0 = qp[lane], v1 = qp[lane + 64];
        float ss = v0 * v0 + v1 * v1;
#pragma unroll
        for (int off = 32; off > 0; off >>= 1) ss += __shfl_xor(ss, off);
        float sc = 1.0f / fmaxf(sqrtf(ss), 1e-12f);
        qint[w * 256 + lane * 2 + i] = v0 * sc;
        qint[w * 256 + (lane + 64) * 2 + i] = v1 * sc;
    }

    float sim2[2][13];
#pragma unroll
    for (int k = 0; k < 13; ++k) { sim2[0][k] = 0.f; sim2[1][k] = 0.f; }

    for (int chunk = 0; chunk < 13; ++chunk) {
        int mbase = chunk << 6;
        __syncthreads();
        // stage 64 keys (transposed) — coalesced global float4 reads
#pragma unroll
        for (int t = 0; t < 8; ++t) {
            int idx = tid + t * 256;          // 0..2047
            int kk = idx >> 5, c4 = idx & 31;
            int m = mbase + kk;
            float4 kv = (m < 800) ? *(const float4*)(knR + (size_t)m * 128 + c4 * 4)
                                  : make_float4(0.f, 0.f, 0.f, 0.f);
            shk[(4 * c4 + 0) * 65 + kk] = kv.x;
            shk[(4 * c4 + 1) * 65 + kk] = kv.y;
            shk[(4 * c4 + 2) * 65 + kk] = kv.z;
            shk[(4 * c4 + 3) * 65 + kk] = kv.w;
        }
        __syncthreads();
        float s0 = sim2[0][chunk], s1 = sim2[1][chunk];
        const float* qw = qint + w * 256;
#pragma unroll 4
        for (int c2 = 0; c2 < 64; ++c2) {   // c = 2*c2, 2*c2+1
            float4 qq = *(const float4*)(qw + c2 * 4);
            float k0 = shk[(2 * c2) * 65 + lane];
            float k1 = shk[(2 * c2 + 1) * 65 + lane];
            s0 += qq.x * k0; s1 += qq.y * k0;
            s0 += qq.z * k1; s1 += qq.w * k1;
        }
        sim2[0][chunk] = s0; sim2[1][chunk] = s1;
    }

#pragma unroll
    for (int i = 0; i < 2; ++i) {
        int g = g0 + i;
        int b = g / 324, q = g - b * 324;
        int h = 23 + q / 18, ww = 23 + q % 18;
        int p = h * 64 + ww;

        float sim[13];
#pragma unroll
        for (int k = 0; k < 13; ++k)
            sim[k] = (lane + (k << 6) < 800) ? sim2[i][k] : NEG_INF;

        // top-11 (values desc, ties -> lower index), verbatim layout m = lane + (k<<6)
        float topv[11]; int topm[11];
#pragma unroll
        for (int t = 0; t < 11; ++t) {
            float bvv = NEG_INF; int bm = 0x7fffffff;
#pragma unroll
            for (int k = 0; k < 13; ++k) {
                if (sim[k] > bvv) { bvv = sim[k]; bm = lane + (k << 6); }
            }
#pragma unroll
            for (int off = 32; off > 0; off >>= 1) {
                float ov = __shfl_xor(bvv, off);
                int om = __shfl_xor(bm, off);
                if (ov > bvv || (ov == bvv && om < bm)) { bvv = ov; bm = om; }
            }
            topv[t] = bvv; topm[t] = bm;
            if ((bm & 63) == lane) {
                int kk = bm >> 6;
#pragma unroll
                for (int k = 0; k < 13; ++k)
                    if (k == kk) sim[k] = NEG_INF;
            }
        }
        // fp64 refinement of the 10/11 boundary
        if (topv[9] - topv[10] < 1e-4f) {
            double s9 = 0.0, s10 = 0.0;
            const float* k9 = knR + (size_t)topm[9] * 128;
            const float* k10 = knR + (size_t)topm[10] * 128;
            for (int c = 0; c < 128; ++c) {
                double qc = (double)qint[w * 256 + c * 2 + i];
                s9 += qc * (double)k9[c];
                s10 += qc * (double)k10[c];
            }
            if ((s10 > s9) || (s10 == s9 && topm[10] < topm[9])) {
                topv[9] = topv[10]; topm[9] = topm[10];
            }
        }
        // softmax over top-10 + weighted gather
        float mx = topv[0];
        float e[10], ssum = 0.f;
#pragma unroll
        for (int t = 0; t < 10; ++t) { e[t] = expf(topv[t] - mx); ssum += e[t]; }
        float inv = 1.0f / ssum;
        float o0 = 0.f, o1 = 0.f;
#pragma unroll
        for (int t = 0; t < 10; ++t) {
            float wt = e[t] * inv;
            const float* vr = values + (size_t)topm[t] * 128;
            o0 += wt * vr[lane];
            o1 += wt * vr[lane + 64];
        }
        float* ob = dcat + ((size_t)b * 256) * 4096 + p;
        ob[(size_t)lane * 4096] = o0;
        ob[(size_t)(lane + 64) * 4096] = o1;
    }
}

// ---------------- constant fill for out-of-region center matches ----------------
__global__ void fill_c0_k(const float* __restrict__ c0, float* __restrict__ dcat) {
    int idx = blockIdx.x * 256 + threadIdx.x;
    int p = idx & 4095;
    int c = (idx >> 12) & 127;
    int b = idx >> 19;
    int h = p >> 6, ww = p & 63;
    if (h >= 23 && h <= 40 && ww >= 23 && ww <= 40) return;
    dcat[((size_t)b * 256 + c) * 4096 + p] = c0[c];
}

// ---------------- skip matching v3: block = 64 queries, 32-row key chunks, 50.2 KB LDS ----------------
__global__ void __launch_bounds__(256) match_skip_v3(
        const float* __restrict__ zs,    // (16,128,64,64)
        const float* __restrict__ hn,    // (800,128) normalized
        const float* __restrict__ hard,  // (800,128) raw
        float* __restrict__ dcat) {      // ch 128..255
    __shared__ float sh[12800];          // shq[64*132] | max(shh[32*132], red[64*17*4])
    float* shq = sh;
    float* shh = sh + 8448;
    int b = blockIdx.x >> 6, pt = blockIdx.x & 63;
    int pbase = pt * 64;
    int tid = threadIdx.x;

    for (int f = tid; f < 8192; f += 256) {
        int c = f >> 6, p = f & 63;
        shq[p * 132 + c] = zs[((size_t)b * 128 + c) * 4096 + pbase + p];
    }

    int qs = tid >> 4, ms = tid & 15;
    float v1[4], v2[4]; int i1[4], i2[4];
#pragma unroll
    for (int u = 0; u < 4; ++u) { v1[u] = NEG_INF; v2[u] = NEG_INF; i1[u] = 0x7fffffff; i2[u] = 0x7fffffff; }

    for (int chunk = 0; chunk < 25; ++chunk) {
        int mbase = chunk * 32;
        __syncthreads();
        for (int f = tid; f < 4096; f += 256) {
            int row = f >> 7, c = f & 127;
            shh[row * 132 + c] = hn[(size_t)(mbase + row) * 128 + c];
        }
        __syncthreads();
        float s[4][2];
#pragma unroll
        for (int u = 0; u < 4; ++u)
#pragma unroll
            for (int j = 0; j < 2; ++j) s[u][j] = 0.f;
        for (int c4 = 0; c4 < 32; ++c4) {
            float4 qv[4], hv[2];
#pragma unroll
            for (int u = 0; u < 4; ++u)
                qv[u] = *(const float4*)(shq + (qs * 4 + u) * 132 + c4 * 4);
#pragma unroll
            for (int j = 0; j < 2; ++j)
                hv[j] = *(const float4*)(shh + (ms + 16 * j) * 132 + c4 * 4);
#pragma unroll
            for (int u = 0; u < 4; ++u)
#pragma unroll
                for (int j = 0; j < 2; ++j)
                    s[u][j] += qv[u].x * hv[j].x + qv[u].y * hv[j].y +
                               qv[u].z * hv[j].z + qv[u].w * hv[j].w;
        }
#pragma unroll
        for (int u = 0; u < 4; ++u)
#pragma unroll
            for (int j = 0; j < 2; ++j) {
                int m = mbase + ms + 16 * j;
                float sv = s[u][j];
                if (sv > v1[u] || (sv == v1[u] && m < i1[u])) {
                    v2[u] = v1[u]; i2[u] = i1[u]; v1[u] = sv; i1[u] = m;
                } else if (sv > v2[u] || (sv == v2[u] && m < i2[u])) {
                    v2[u] = sv; i2[u] = m;
                }
            }
    }
    __syncthreads();
    float4* red = (float4*)(sh + 8448);  // [64 q][17 slots]
#pragma unroll
    for (int u = 0; u < 4; ++u)
        red[(qs * 4 + u) * 17 + ms] =
            make_float4(v1[u], v2[u], __int_as_float(i1[u]), __int_as_float(i2[u]));
    __syncthreads();
    if (tid < 64) {
        int q = tid;
        float V1 = NEG_INF, V2 = NEG_INF; int I1 = 0x7fffffff, I2 = 0x7fffffff;
        for (int k = 0; k < 16; ++k) {
            float4 e = red[q * 17 + k];
            float cv[2] = { e.x, e.y };
            int ci_[2] = { __float_as_int(e.z), __float_as_int(e.w) };
#pragma unroll
            for (int t = 0; t < 2; ++t) {
                float v = cv[t]; int i = ci_[t];
                if (v > V1 || (v == V1 && i < I1)) { V2 = V1; I2 = I1; V1 = v; I1 = i; }
                else if (v > V2 || (v == V2 && i < I2)) { V2 = v; I2 = i; }
            }
        }
        float qn2 = 0.f;
        for (int c = 0; c < 128; ++c) { float qc = shq[q * 132 + c]; qn2 += qc * qc; }
        float tau = 1e-4f * sqrtf(qn2) + 1e-12f;
        int bi = I1;
        if (V1 - V2 < tau && I2 != 0x7fffffff) {
            double d1 = 0.0, d2 = 0.0;
            const float* h1 = hn + (size_t)I1 * 128;
            const float* h2 = hn + (size_t)I2 * 128;
            for (int c = 0; c < 128; ++c) {
                double qc = (double)shq[q * 132 + c];
                d1 += qc * (double)h1[c];
                d2 += qc * (double)h2[c];
            }
            if ((d2 > d1) || (d2 == d1 && I2 < I1)) bi = I2;
        }
        const float* hr = hard + (size_t)bi * 128;
        float* ob = dcat + ((size_t)b * 256 + 128) * 4096 + pbase + q;
        for (int c = 0; c < 128; ++c) ob[(size_t)c * 4096] = hr[c];
    }
}

// ---------------- decoder conv1 v4: weight-staged LDS, 4 px/thread, K-split 2 ----------------
__global__ void __launch_bounds__(256, 2) dec1_v4(
        const float* __restrict__ dcat, // (16,256,64,64)
        const float* __restrict__ w,    // (64,256,3,3)
        float* __restrict__ pA,         // partial ksplit 0
        float* __restrict__ pB) {       // partial ksplit 1
    __shared__ float xs[2][4760];       // 4 ci x 34x35 halo tile
    __shared__ float wsh[2][768];       // 4 ci x 16 co x 12
    int bx = blockIdx.x;
    int b = bx >> 5, rem = bx & 31;
    int cog = rem >> 3, tile = (rem >> 1) & 3, ks = rem & 1;
    int ph0 = (tile >> 1) * 32, pw0 = (tile & 1) * 32;
    int tid = threadIdx.x;
    int pr = tid >> 4, pc = tid & 15;

    const float* ib = dcat + ((size_t)b * 256 + (size_t)ks * 128) * 4096;
    const float* wb = w + (size_t)(cog * 16) * 2304 + (size_t)ks * 128 * 9;

    int xg[19];
#pragma unroll
    for (int k = 0; k < 19; ++k) {
        int f = tid + k * 256;
        xg[k] = -1;
        if (f < 4760) {
            int ci_l = f / 1190, pos = f % 1190;
            int r = pos / 35, c = pos % 35;
            int row = ph0 - 1 + r, col = pw0 - 1 + c;
            if (c < 34 && row >= 0 && row < 64 && col >= 0 && col < 64)
                xg[k] = ci_l * 4096 + row * 64 + col;
        }
    }
    int wg[3], wl[3];
#pragma unroll
    for (int k = 0; k < 3; ++k) {
        int t = tid + k * 256;
        wg[k] = -1; wl[k] = 0;
        if (t < 576) {
            int ci_l = t / 144, r2 = t % 144;
            int co = r2 / 9, j = r2 % 9;
            wg[k] = co * 2304 + ci_l * 9 + j;
            wl[k] = ci_l * 192 + co * 12 + j;
        }
    }

#pragma unroll
    for (int k = 0; k < 19; ++k) {
        int f = tid + k * 256;
        if (f < 4760) xs[0][f] = (xg[k] >= 0) ? ib[xg[k]] : 0.f;
    }
#pragma unroll
    for (int k = 0; k < 3; ++k)
        if (wg[k] >= 0) wsh[0][wl[k]] = wb[wg[k]];
    __syncthreads();

    float acc[16][4];
#pragma unroll
    for (int co = 0; co < 16; ++co)
#pragma unroll
        for (int q = 0; q < 4; ++q) acc[co][q] = 0.f;

    for (int chunk = 0; chunk < 32; ++chunk) {
        int cur = chunk & 1;
        float pfx[19], pfw[3];
        if (chunk < 31) {
            const float* ibn = ib + (size_t)(chunk + 1) * 4 * 4096;
            const float* wbn = wb + (chunk + 1) * 36;
#pragma unroll
            for (int k = 0; k < 19; ++k) {
                int f = tid + k * 256;
                if (f < 4760) pfx[k] = (xg[k] >= 0) ? ibn[xg[k]] : 0.f;
            }
#pragma unroll
            for (int k = 0; k < 3; ++k)
                if (wg[k] >= 0) pfw[k] = wbn[wg[k]];
        }
#pragma unroll 2
        for (int ci_l = 0; ci_l < 4; ++ci_l) {
            const float* xp = &xs[cur][ci_l * 1190 + (2 * pr) * 35 + 2 * pc];
            float xw[4][4];
#pragma unroll
            for (int r = 0; r < 4; ++r)
#pragma unroll
                for (int c = 0; c < 4; ++c) xw[r][c] = xp[r * 35 + c];
            const float* wp = &wsh[cur][ci_l * 192];
#pragma unroll
            for (int co = 0; co < 16; ++co) {
                float4 w0 = *(const float4*)(wp + co * 12);
                float4 w1 = *(const float4*)(wp + co * 12 + 4);
                float4 w2 = *(const float4*)(wp + co * 12 + 8);
                float wv[9] = { w0.x, w0.y, w0.z, w0.w, w1.x, w1.y, w1.z, w1.w, w2.x };
#pragma unroll
                for (int q = 0; q < 4; ++q) {
                    int qr = q >> 1, qc = q & 1;
                    float s = acc[co][q];
#pragma unroll
                    for (int kh = 0; kh < 3; ++kh)
#pragma unroll
                        for (int kw = 0; kw < 3; ++kw)
                            s += xw[qr + kh][qc + kw] * wv[kh * 3 + kw];
                    acc[co][q] = s;
                }
            }
        }
        if (chunk < 31) {
#pragma unroll
            for (int k = 0; k < 19; ++k) {
                int f = tid + k * 256;
                if (f < 4760) xs[1 - cur][f] = pfx[k];
            }
#pragma unroll
            for (int k = 0; k < 3; ++k)
                if (wg[k] >= 0) wsh[1 - cur][wl[k]] = pfw[k];
            __syncthreads();
        }
    }
    float* ob = ((ks == 0) ? pA : pB) + ((size_t)b * 64 + cog * 16) * 4096;
#pragma unroll
    for (int co = 0; co < 16; ++co)
#pragma unroll
        for (int q = 0; q < 4; ++q) {
            int row = ph0 + 2 * pr + (q >> 1), col = pw0 + 2 * pc + (q & 1);
            ob[(size_t)co * 4096 + row * 64 + col] = acc[co][q];
        }
}

// ---------------- dec1 partial reduce: d1 = relu(pA + pB + bias), in-place over pA ----------------
__global__ void dec1_add_k(float* __restrict__ pA, const float* __restrict__ pB,
                           const float* __restrict__ bias) {
    int idx = blockIdx.x * 256 + threadIdx.x;  // 4194304
    int c = (idx >> 12) & 63;
    float v = pA[idx] + pB[idx] + bias[c];
    pA[idx] = fmaxf(v, 0.f);
}

// ---------------- transposed conv v2: quad-parity, 16 co per thread ----------------
template <int CIN, int COUT, int COG, int H>
__global__ void __launch_bounds__(256) tconv_v2(
        const float* __restrict__ x,   // (16,CIN,H,H)
        const float* __restrict__ w,   // (CIN,COUT,4,4)
        const float* __restrict__ bias,
        float* __restrict__ out) {     // (16,COUT,2H,2H)
    constexpr int NCOG = COUT / COG;
    constexpr int TPS = H / 16;
    constexpr int TILES = TPS * TPS;
    constexpr int HO = 2 * H;
    int bx = blockIdx.x;
    int b = bx / (NCOG * TILES), rem = bx % (NCOG * TILES);
    int cog = rem / TILES, tile = rem % TILES;
    int ti = tile / TPS, tj = tile % TPS;
    int tid = threadIdx.x;
    int i = ti * 16 + (tid >> 4);
    int j = tj * 16 + (tid & 15);

    float acc[2][2][COG];
#pragma unroll
    for (int pr = 0; pr < 2; ++pr)
#pragma unroll
        for (int pc = 0; pc < 2; ++pc)
#pragma unroll
            for (int co = 0; co < COG; ++co) acc[pr][pc][co] = 0.f;

    const float* xb = x + (size_t)b * CIN * H * H;
    for (int ci = 0; ci < CIN; ++ci) {
        const float* xp = xb + (size_t)ci * H * H;
        float xr[3][3];
#pragma unroll
        for (int dr = 0; dr < 3; ++dr) {
            int gr = i - 1 + dr;
            bool vr = (gr >= 0 && gr < H);
#pragma unroll
            for (int dc = 0; dc < 3; ++dc) {
                int gc = j - 1 + dc;
                xr[dr][dc] = (vr && gc >= 0 && gc < H) ? xp[gr * H + gc] : 0.f;
            }
        }
#pragma unroll
        for (int co = 0; co < COG; ++co) {
            const float* wp = w + (((size_t)ci * COUT + cog * COG + co) << 4);
            float wr[16];
#pragma unroll
            for (int k = 0; k < 16; ++k) wr[k] = wp[k];
#pragma unroll
            for (int pr = 0; pr < 2; ++pr)
#pragma unroll
                for (int a = 0; a < 2; ++a)
#pragma unroll
                    for (int pc = 0; pc < 2; ++pc)
#pragma unroll
                        for (int bb = 0; bb < 2; ++bb)
                            acc[pr][pc][co] += xr[pr + a][pc + bb] *
                                               wr[(3 - pr - 2 * a) * 4 + (3 - pc - 2 * bb)];
        }
    }
#pragma unroll
    for (int co = 0; co < COG; ++co) {
        float bv = bias[cog * COG + co];
        float* ob = out + ((size_t)b * COUT + cog * COG + co) * HO * HO;
#pragma unroll
        for (int pr = 0; pr < 2; ++pr)
#pragma unroll
            for (int pc = 0; pc < 2; ++pc)
                ob[(2 * i + pr) * HO + 2 * j + pc] = fmaxf(acc[pr][pc][co] + bv, 0.f);
    }
}

// ---------------- final conv (16->1) 3x3, 4 px per thread ----------------
__global__ void final_v2(const float* __restrict__ t2,  // (16,16,256,256)
                         const float* __restrict__ w,   // (1,16,3,3)
                         const float* __restrict__ bias,
                         float* __restrict__ out) {     // (16,1,256,256)
    int g = blockIdx.x * 256 + threadIdx.x;
    int pxb = g * 4;
    int b = pxb >> 16, p = pxb & 65535;
    int h = p >> 8, c0 = p & 255;
    const float* tb = t2 + (size_t)b * 16 * 65536;
    float acc[4];
    float bv = bias[0];
#pragma unroll
    for (int t = 0; t < 4; ++t) acc[t] = bv;
    for (int ci = 0; ci < 16; ++ci) {
        const float* pp = tb + (size_t)ci * 65536;
        const float* w9 = w + ci * 9;
        float win[3][6];
#pragma unroll
        for (int dr = 0; dr < 3; ++dr) {
            int rr = h - 1 + dr;
            bool vr = (rr >= 0 && rr < 256);
#pragma unroll
            for (int dc = 0; dc < 6; ++dc) {
                int cc = c0 - 1 + dc;
                win[dr][dc] = (vr && cc >= 0 && cc < 256) ? pp[rr * 256 + cc] : 0.f;
            }
        }
#pragma unroll
        for (int t = 0; t < 4; ++t)
#pragma unroll
            for (int dr = 0; dr < 3; ++dr)
#pragma unroll
                for (int dc = 0; dc < 3; ++dc)
                    acc[t] += win[dr][t + dc] * w9[dr * 3 + dc];
    }
    *(float4*)(out + pxb) = make_float4(acc[0], acc[1], acc[2], acc[3]);
}

// ---------------- launch ----------------
extern "C" void kernel_launch(void* const* d_in, const int* in_sizes, int n_in,
                              void* d_out, int out_size, void* d_ws, size_t ws_size,
                              hipStream_t stream) {
    (void)in_sizes; (void)n_in; (void)out_size; (void)ws_size;
    const float* x     = (const float*)d_in[0];
    const float* cw1   = (const float*)d_in[1];
    const float* cb1   = (const float*)d_in[2];
    const float* cw2   = (const float*)d_in[3];
    const float* cb2   = (const float*)d_in[4];
    const float* sw1   = (const float*)d_in[5];
    const float* sb1   = (const float*)d_in[6];
    const float* sw2   = (const float*)d_in[7];
    const float* sb2   = (const float*)d_in[8];
    const float* mkeys = (const float*)d_in[9];
    const float* mvals = (const float*)d_in[10];
    const float* mhard = (const float*)d_in[11];
    const float* dw1   = (const float*)d_in[12];
    const float* db1   = (const float*)d_in[13];
    const float* tw1   = (const float*)d_in[14];
    const float* tb1   = (const float*)d_in[15];
    const float* tw2   = (const float*)d_in[16];
    const float* tb2   = (const float*)d_in[17];
    const float* dw2   = (const float*)d_in[18];
    const float* db2   = (const float*)d_in[19];
    float* out = (float*)d_out;
    float* ws  = (float*)d_ws;

    const size_t OFF_KN  = 0;                   // knR: 800*128
    const size_t OFF_HN  = 102400;              // hn:  800*128
    const size_t OFF_C0  = 204800;              // c0:  128
    const size_t OFF_R14 = 204928;              // zc1 -> zs -> t1
    const size_t OFF_R2  = OFF_R14 + 8388608;   // dec1 partial B
    const size_t OFF_R3  = OFF_R2 + 8388608;    // zs1 -> dec1 partial A / d1
    const size_t OFF_R5  = OFF_R3 + 4194304;    // dcat -> t2
    const size_t OFF_ZCQ = OFF_R5 + 16777216;   // zcq: 16*324*128 = 663552

    float* knR  = ws + OFF_KN;
    float* hn   = ws + OFF_HN;
    float* c0   = ws + OFF_C0;
    float* zc1  = ws + OFF_R14;
    float* zs   = ws + OFF_R14;
    float* t1   = ws + OFF_R14;
    float* pB   = ws + OFF_R2;
    float* zs1  = ws + OFF_R3;
    float* d1b  = ws + OFF_R3;
    float* dcat = ws + OFF_R5;
    float* t2   = ws + OFF_R5;
    float* zcq  = ws + OFF_ZCQ;

    prep_norm_k<<<800, 128, 0, stream>>>(mkeys, mhard, knR, hn);
    prep_c0_k<<<1, 128, 0, stream>>>(mvals, c0);

    ce1_k<<<16 * 2 * 6, 256, 0, stream>>>(x, cw1, cb1, zc1);
    se1_k<<<16 * 64, 256, 0, stream>>>(x, sw1, sb1, zs1);
    ce2_v3<<<16 * 16, 256, 0, stream>>>(zc1, cw2, cb2, zcq);
    se2_v2<<<16 * 16 * 16, 256, 0, stream>>>(zs1, sw2, sb2, zs);  // overwrites zc1 (dead)

    match_center_v2<<<648, 256, 0, stream>>>(zcq, knR, mvals, dcat);
    fill_c0_k<<<32768, 256, 0, stream>>>(c0, dcat);
    match_skip_v3<<<16 * 64, 256, 0, stream>>>(zs, hn, mhard, dcat);

    dec1_v4<<<512, 256, 0, stream>>>(dcat, dw1, d1b, pB);
    dec1_add_k<<<16384, 256, 0, stream>>>(d1b, pB, db1);

    tconv_v2<64, 32, 16, 64><<<16 * 2 * 16, 256, 0, stream>>>(d1b, tw1, tb1, t1);   // overwrites zs (dead)
    tconv_v2<32, 16, 16, 128><<<16 * 1 * 64, 256, 0, stream>>>(t1, tw2, tb2, t2);   // overwrites dcat (dead)
    final_v2<<<1024, 256, 0, stream>>>(t2, dw2, db2, out);
}